// Round 4
// baseline (1109.594 us; speedup 1.0000x reference)
//
#include <hip/hip_runtime.h>
#include <math.h>

#define NEGV -1e9f

typedef short bf16x8 __attribute__((ext_vector_type(8)));
typedef float f32x4 __attribute__((ext_vector_type(4)));
typedef unsigned short ushort8v __attribute__((ext_vector_type(8)));

static __device__ __forceinline__ unsigned short f2bf(float f) {
  unsigned int u = __float_as_uint(f);
  unsigned int r = (u + 0x7fffu + ((u >> 16) & 1u)) >> 16;
  return (unsigned short)r;
}

// counted vmcnt wait (immediate must be a literal token)
#define VMCNT(n) asm volatile("s_waitcnt vmcnt(" #n ")" ::: "memory")
#define LGKM0()  asm volatile("s_waitcnt lgkmcnt(0)" ::: "memory")

// ---------------------------------------------------------------------------
// reductions
// ---------------------------------------------------------------------------
__device__ __forceinline__ float wred_max(float v) {
  #pragma unroll
  for (int o = 32; o > 0; o >>= 1) v = fmaxf(v, __shfl_down(v, o, 64));
  return v;
}
__device__ __forceinline__ float wred_sum(float v) {
  #pragma unroll
  for (int o = 32; o > 0; o >>= 1) v += __shfl_down(v, o, 64);
  return v;
}

// ---------------------------------------------------------------------------
// masked softmax over LAST dim. X: (batch, R, Cn); mask: (batch, Cn)
// ---------------------------------------------------------------------------
__global__ __launch_bounds__(256)
void softmax_row_mask(const float* __restrict__ X, const int* __restrict__ mask,
                      float* __restrict__ Y, unsigned short* __restrict__ Ybf,
                      int R, int Cn)
{
  int bz = blockIdx.y, r = blockIdx.x, tid = threadIdx.x;
  const float* xr = X + ((size_t)bz * R + r) * Cn;
  const int*   mr = mask + (size_t)bz * Cn;
  float*       yr = Y ? (Y + ((size_t)bz * R + r) * Cn) : nullptr;
  unsigned short* yb = Ybf ? (Ybf + ((size_t)bz * R + r) * Cn) : nullptr;
  __shared__ float sred[4];

  float mx = -INFINITY;
  for (int i = tid; i < Cn; i += 256) {
    float v = (mr[i] != 0) ? xr[i] : NEGV;
    mx = fmaxf(mx, v);
  }
  float wm = wred_max(mx);
  if ((tid & 63) == 0) sred[tid >> 6] = wm;
  __syncthreads();
  mx = fmaxf(fmaxf(sred[0], sred[1]), fmaxf(sred[2], sred[3]));
  __syncthreads();

  float s = 0.f;
  for (int i = tid; i < Cn; i += 256) {
    float v = (mr[i] != 0) ? xr[i] : NEGV;
    s += expf(v - mx);
  }
  float wsv = wred_sum(s);
  if ((tid & 63) == 0) sred[tid >> 6] = wsv;
  __syncthreads();
  s = sred[0] + sred[1] + sred[2] + sred[3];
  float inv = 1.0f / s;

  for (int i = tid; i < Cn; i += 256) {
    float v = (mr[i] != 0) ? xr[i] : NEGV;
    float o = expf(v - mx) * inv;
    if (yr) yr[i] = o;
    if (yb) yb[i] = f2bf(o);
  }
}

// ---------------------------------------------------------------------------
// batched f32 tiled transpose: X (batch, R, C) -> Y (batch, C, R)
// ---------------------------------------------------------------------------
__global__ __launch_bounds__(256)
void transp_f32(const float* __restrict__ X, float* __restrict__ Y,
                int R, int C, long sX, long sY)
{
  int bz = blockIdx.z;
  X += (size_t)bz * sX;
  Y += (size_t)bz * sY;
  __shared__ float T[64][65];
  int c0 = blockIdx.x * 64, r0 = blockIdx.y * 64;
  int t = threadIdx.x;
  int tr = t >> 4, tc4 = (t & 15) * 4;
  #pragma unroll
  for (int rr = 0; rr < 4; ++rr) {
    int r = tr + rr * 16;
    float4 v = make_float4(0.f, 0.f, 0.f, 0.f);
    if (c0 + tc4 < C)
      v = *reinterpret_cast<const float4*>(X + (size_t)(r0 + r) * C + c0 + tc4);
    T[r][tc4 + 0] = v.x; T[r][tc4 + 1] = v.y;
    T[r][tc4 + 2] = v.z; T[r][tc4 + 3] = v.w;
  }
  __syncthreads();
  #pragma unroll
  for (int rr = 0; rr < 4; ++rr) {
    int cc = tr + rr * 16;
    int gc = c0 + cc;
    if (gc < C) {
      float4 o = make_float4(T[tc4 + 0][cc], T[tc4 + 1][cc], T[tc4 + 2][cc], T[tc4 + 3][cc]);
      *reinterpret_cast<float4*>(Y + (size_t)gc * R + r0 + tc4) = o;
    }
  }
}

// ---------------------------------------------------------------------------
// transpose V: (batch, 96, 768) f32 -> VTb (batch, 768, 96) bf16
// ---------------------------------------------------------------------------
__global__ __launch_bounds__(256)
void transpV(const float* __restrict__ V, unsigned short* __restrict__ VT)
{
  int bz = blockIdx.z;
  const float* Vb = V + (size_t)bz * 96 * 768;
  unsigned short* Yb = VT + (size_t)bz * 768 * 96;
  __shared__ float T[64][65];
  int c0 = blockIdx.x * 64, r0 = blockIdx.y * 64;
  int t = threadIdx.x;
  int tr = t >> 4, tc4 = (t & 15) * 4;
  #pragma unroll
  for (int rr = 0; rr < 4; ++rr) {
    int r = tr + rr * 16;
    int gr = r0 + r;
    float4 v = make_float4(0.f, 0.f, 0.f, 0.f);
    if (gr < 96)
      v = *reinterpret_cast<const float4*>(Vb + (size_t)gr * 768 + c0 + tc4);
    T[r][tc4 + 0] = v.x; T[r][tc4 + 1] = v.y;
    T[r][tc4 + 2] = v.z; T[r][tc4 + 3] = v.w;
  }
  __syncthreads();
  #pragma unroll
  for (int rr = 0; rr < 4; ++rr) {
    int cc = tr + rr * 16;
    int gc = c0 + cc;
    #pragma unroll
    for (int e = 0; e < 4; ++e) {
      int gr = r0 + tc4 + e;
      if (gr < 96) Yb[(size_t)gc * 96 + gr] = f2bf(T[tc4 + e][cc]);
    }
  }
}

// ---------------------------------------------------------------------------
// concat to bf16: Mc (6144, 2304) = [x | f | x*f] row-major bf16.
// (the x-f segment is folded into the SFU weights: m@W = x@(Wa+Wd) +
//  f@(Wb-Wd) + (x*f)@Wc  -- exact identity, K 3072 -> 2304)
// ---------------------------------------------------------------------------
__global__ __launch_bounds__(256)
void concat_bf16(const float* __restrict__ X, const float* __restrict__ F,
                 unsigned short* __restrict__ Mc)
{
  int idx = blockIdx.x * 256 + threadIdx.x;
  int m  = idx / 96;
  int kk = (idx - m * 96) * 8;
  const float* xp = X + (size_t)m * 768 + kk;
  const float* fp = F + (size_t)m * 768 + kk;
  float4 a0 = *reinterpret_cast<const float4*>(xp);
  float4 a1 = *reinterpret_cast<const float4*>(xp + 4);
  float4 b0 = *reinterpret_cast<const float4*>(fp);
  float4 b1 = *reinterpret_cast<const float4*>(fp + 4);
  float xa[8] = {a0.x, a0.y, a0.z, a0.w, a1.x, a1.y, a1.z, a1.w};
  float fa[8] = {b0.x, b0.y, b0.z, b0.w, b1.x, b1.y, b1.z, b1.w};
  ushort8v o0, o1, o2;
  #pragma unroll
  for (int i = 0; i < 8; ++i) {
    o0[i] = f2bf(xa[i]);
    o1[i] = f2bf(fa[i]);
    o2[i] = f2bf(xa[i] * fa[i]);
  }
  unsigned short* base = Mc + (size_t)m * 2304 + kk;
  *reinterpret_cast<ushort8v*>(base)        = o0;
  *reinterpret_cast<ushort8v*>(base +  768) = o1;
  *reinterpret_cast<ushort8v*>(base + 1536) = o2;
}

// ---------------------------------------------------------------------------
// batched transpose+convert for the 4 small (768x768) weights, z picks tensor
// grid (12, 12, 4)
// ---------------------------------------------------------------------------
__global__ __launch_bounds__(256)
void transp_cast4(const float* __restrict__ W0, const float* __restrict__ W1a,
                  const float* __restrict__ W2a, const float* __restrict__ W3a,
                  unsigned short* __restrict__ Wt)
{
  int z = blockIdx.z;
  const float* W = (z == 0) ? W0 : (z == 1) ? W1a : (z == 2) ? W2a : W3a;
  unsigned short* Y = Wt + (size_t)z * 768 * 768;
  __shared__ float T[64][65];
  int n0 = blockIdx.x * 64, k0 = blockIdx.y * 64;
  int t = threadIdx.x;
  int tr = t >> 4, tc4 = (t & 15) * 4;
  #pragma unroll
  for (int r = 0; r < 4; ++r) {
    int k = tr + r * 16;
    float4 v = *reinterpret_cast<const float4*>(W + (size_t)(k0 + k) * 768 + n0 + tc4);
    T[k][tc4 + 0] = v.x; T[k][tc4 + 1] = v.y; T[k][tc4 + 2] = v.z; T[k][tc4 + 3] = v.w;
  }
  __syncthreads();
  #pragma unroll
  for (int r = 0; r < 4; ++r) {
    int n = tr + r * 16;
    ushort4 o;
    o.x = f2bf(T[tc4 + 0][n]); o.y = f2bf(T[tc4 + 1][n]);
    o.z = f2bf(T[tc4 + 2][n]); o.w = f2bf(T[tc4 + 3][n]);
    *reinterpret_cast<ushort4*>(Y + (size_t)(n0 + n) * 768 + k0 + tc4) = o;
  }
}

// ---------------------------------------------------------------------------
// Folded transpose+convert for the 2 big (3072x768) SFU weights, z picks.
// Emits Wt (768, 2304) bf16 with fold:
//   k in [0,768):    Wa[k] + Wd[k]   (rows k and k+2304 of W)
//   k in [768,1536): Wb[k] - Wd[k]   (rows k and k+1536 of W)
//   k in [1536,2304): Wc[k]          (row k of W)
// grid (12, 36, 2)
// ---------------------------------------------------------------------------
__global__ __launch_bounds__(256)
void transp_cast2(const float* __restrict__ Wa, const float* __restrict__ Wb,
                  unsigned short* __restrict__ Wt)
{
  const float* W = blockIdx.z ? Wb : Wa;
  unsigned short* Y = Wt + (size_t)blockIdx.z * 768 * 2304;
  __shared__ float T[64][65];
  int n0 = blockIdx.x * 64, k0 = blockIdx.y * 64;
  int t = threadIdx.x;
  int tr = t >> 4, tc4 = (t & 15) * 4;
  #pragma unroll
  for (int r = 0; r < 4; ++r) {
    int k = tr + r * 16;
    int gk = k0 + k;
    float4 v = *reinterpret_cast<const float4*>(W + (size_t)gk * 768 + n0 + tc4);
    if (gk < 768) {
      float4 u = *reinterpret_cast<const float4*>(W + (size_t)(gk + 2304) * 768 + n0 + tc4);
      v.x += u.x; v.y += u.y; v.z += u.z; v.w += u.w;
    } else if (gk < 1536) {
      float4 u = *reinterpret_cast<const float4*>(W + (size_t)(gk + 1536) * 768 + n0 + tc4);
      v.x -= u.x; v.y -= u.y; v.z -= u.z; v.w -= u.w;
    }
    T[k][tc4 + 0] = v.x; T[k][tc4 + 1] = v.y; T[k][tc4 + 2] = v.z; T[k][tc4 + 3] = v.w;
  }
  __syncthreads();
  #pragma unroll
  for (int r = 0; r < 4; ++r) {
    int n = tr + r * 16;
    ushort4 o;
    o.x = f2bf(T[tc4 + 0][n]); o.y = f2bf(T[tc4 + 1][n]);
    o.z = f2bf(T[tc4 + 2][n]); o.w = f2bf(T[tc4 + 3][n]);
    *reinterpret_cast<ushort4*>(Y + (size_t)(n0 + n) * 2304 + k0 + tc4) = o;
  }
}

// ---------------------------------------------------------------------------
// batched transpose+convert: W (batch, K, 768) f32 -> Wt (batch, 768, K) bf16
// ---------------------------------------------------------------------------
__global__ __launch_bounds__(256)
void transp_cast(const float* __restrict__ W, unsigned short* __restrict__ Wt,
                 int K, long sW, long sWt)
{
  int bz = blockIdx.z;
  W  += (size_t)bz * sW;
  Wt += (size_t)bz * sWt;
  __shared__ float T[64][65];
  int n0 = blockIdx.x * 64, k0 = blockIdx.y * 64;
  int t = threadIdx.x;
  int tr = t >> 4, tc4 = (t & 15) * 4;
  #pragma unroll
  for (int r = 0; r < 4; ++r) {
    int k = tr + r * 16;
    float4 v = *reinterpret_cast<const float4*>(W + (size_t)(k0 + k) * 768 + n0 + tc4);
    T[k][tc4 + 0] = v.x; T[k][tc4 + 1] = v.y; T[k][tc4 + 2] = v.z; T[k][tc4 + 3] = v.w;
  }
  __syncthreads();
  #pragma unroll
  for (int r = 0; r < 4; ++r) {
    int n = tr + r * 16;
    ushort4 o;
    o.x = f2bf(T[tc4 + 0][n]); o.y = f2bf(T[tc4 + 1][n]);
    o.z = f2bf(T[tc4 + 2][n]); o.w = f2bf(T[tc4 + 3][n]);
    *reinterpret_cast<ushort4*>(Wt + (size_t)(n0 + n) * K + k0 + tc4) = o;
  }
}

// ---------------------------------------------------------------------------
// flat f32 -> bf16 cast. n8 = elems/8.
// ---------------------------------------------------------------------------
__global__ __launch_bounds__(256)
void cast_bf16(const float* __restrict__ X, unsigned short* __restrict__ Y, int n8)
{
  int idx = blockIdx.x * 256 + threadIdx.x;
  if (idx >= n8) return;
  float4 a0 = *reinterpret_cast<const float4*>(X + (size_t)idx * 8);
  float4 a1 = *reinterpret_cast<const float4*>(X + (size_t)idx * 8 + 4);
  ushort8v o;
  o[0] = f2bf(a0.x); o[1] = f2bf(a0.y); o[2] = f2bf(a0.z); o[3] = f2bf(a0.w);
  o[4] = f2bf(a1.x); o[5] = f2bf(a1.y); o[6] = f2bf(a1.z); o[7] = f2bf(a1.w);
  *reinterpret_cast<ushort8v*>(Y + (size_t)idx * 8) = o;
}

// ===========================================================================
// Swizzled LDS layout (verified r9, conflicts -> 0). Per-row permutation
// depends only on row&7 -> invariant across buffers/tiles.
//
// 3-buffer, register-prefetch pipeline (this round):
//  body(kt): vmcnt(L)  [tile kt+1 landed; kt+2 in flight]
//            lgkmcnt(0) [own reads of tile kt (issued last body) complete
//                        -> buffer kt%3 safe to re-fill after the barrier]
//            s_barrier ; sched_barrier(0)
//            STAGE(kt+3 -> buf[kt%3]) ; ds_read tile kt+1 -> OTHER reg set
//            setprio(1) ; MFMA on regs of tile kt ; setprio(0)
// ds latency is off the critical path (reads complete under the MFMA cluster
// + next barrier). ds_reads stay compiler-visible so the waitcnt pass emits
// counted lgkm waits. Static reg indexing via two named sets (X/Y).
// NT >= 3 required (min K here is 96 -> NT=3).
// ===========================================================================

// ---------------------------------------------------------------------------
// Generic MFMA GEMM, 96x64 tile, reg-prefetch pipelined, BK=32, 256 thr
// (4 waves 2x2, each wave 48Mx32N: i=3, j=2), swizzled LDS.
// grid (ceil(N/64), M/96, batch). M mult 96. N clamped.
// ---------------------------------------------------------------------------
template<int NB>
__global__ __launch_bounds__(256)
void mfma_gemm(const unsigned short* __restrict__ A,
               const unsigned short* __restrict__ Bt0,
               const unsigned short* __restrict__ Bt1,
               const float* __restrict__ bias0, const float* __restrict__ bias1,
               const float* __restrict__ alphap, const float* __restrict__ C0,
               float* __restrict__ F0, float* __restrict__ F1,
               unsigned short* __restrict__ O0, unsigned short* __restrict__ O1,
               int M, int N, int K,
               long sA, long sB, long sC0, long sC,
               int relu, int zerodiag)
{
  __shared__ unsigned short As[3][3072];    // 96 x 32 (swizzled granules)
  __shared__ unsigned short Bs0[3][2048];   // 64 x 32
  __shared__ unsigned short Bs1[3][NB == 2 ? 2048 : 16];

  int bz = blockIdx.z;
  A   += (size_t)bz * sA;
  Bt0 += (size_t)bz * sB;
  if (NB == 2) Bt1 += (size_t)bz * sB;
  const float* C0b = C0 ? (C0 + (size_t)bz * sC0) : nullptr;

  int tid = threadIdx.x;
  int w = tid >> 6, l = tid & 63;
  int m0 = blockIdx.y * 96, n0 = blockIdx.x * 64;
  int wr = w >> 1, wc = w & 1;

  int rS = w * 16 + (l >> 2);
  int g8 = (((l & 3) ^ ((l >> 3) & 3))) * 8;
  int rB = n0 + rS; if (rB > N - 1) rB = N - 1;
  const unsigned short* srcA0 = A + (size_t)(m0 + rS) * K + g8;       // rows [0,64)
  const unsigned short* srcA1 = A + (size_t)(m0 + 64 + rS) * K + g8;  // rows [64,96), w<2 only
  const unsigned short* srcB0 = Bt0 + (size_t)rB * K + g8;
  const unsigned short* srcB1 = (NB == 2) ? Bt1 + (size_t)rB * K + g8 : nullptr;
  int wb = w * 256;  // uint base within a wave's 1KB chunk

#define GG_STAGE(kt, bi) do { int kk0 = (kt) * 32;                                                                        \
    __builtin_amdgcn_global_load_lds((const unsigned int*)(srcA0 + kk0), (unsigned int*)&As[bi][0]  + wb,        16, 0, 0); \
    if (w < 2)                                                                                                            \
      __builtin_amdgcn_global_load_lds((const unsigned int*)(srcA1 + kk0), (unsigned int*)&As[bi][0] + 1024 + wb, 16, 0, 0); \
    __builtin_amdgcn_global_load_lds((const unsigned int*)(srcB0 + kk0), (unsigned int*)&Bs0[bi][0] + wb,        16, 0, 0); \
    if (NB == 2)                                                                                                          \
      __builtin_amdgcn_global_load_lds((const unsigned int*)(srcB1 + kk0), (unsigned int*)&Bs1[bi][0] + wb,      16, 0, 0); \
  } while (0)

#define GG_READ(AF, B0v, B1v, bi) do {                                                        \
    _Pragma("unroll")                                                                          \
    for (int i = 0; i < 3; ++i)                                                                \
      AF[i] = *reinterpret_cast<const bf16x8*>(&As[bi][(wr * 48 + i * 16 + (l & 15)) * 32 + prm]); \
    _Pragma("unroll")                                                                          \
    for (int j = 0; j < 2; ++j) {                                                              \
      int off = (wc * 32 + j * 16 + (l & 15)) * 32 + prm;                                      \
      B0v[j] = *reinterpret_cast<const bf16x8*>(&Bs0[bi][off]);                                \
      if (NB == 2) B1v[j] = *reinterpret_cast<const bf16x8*>(&Bs1[bi][off]);                   \
    }                                                                                          \
  } while (0)

#define GG_BODY(kt, CAF, CB0, CB1, PAF, PB0, PB1, bS, bR) do {                                 \
    if ((kt) <= NT - 3) {                                                                      \
      if (NB == 2) { if (w < 2) VMCNT(4); else VMCNT(3); }                                     \
      else         { if (w < 2) VMCNT(3); else VMCNT(2); }                                     \
    } else VMCNT(0);                                                                           \
    LGKM0();                                                                                   \
    __builtin_amdgcn_s_barrier();                                                              \
    __builtin_amdgcn_sched_barrier(0);                                                         \
    if ((kt) + 3 < NT) GG_STAGE((kt) + 3, bS);                                                 \
    if ((kt) + 1 < NT) GG_READ(PAF, PB0, PB1, bR);                                             \
    __builtin_amdgcn_s_setprio(1);                                                             \
    _Pragma("unroll")                                                                          \
    for (int j = 0; j < 2; ++j) {                                                              \
      _Pragma("unroll")                                                                        \
      for (int i = 0; i < 3; ++i)                                                              \
        a0[i][j] = __builtin_amdgcn_mfma_f32_16x16x32_bf16(CAF[i], CB0[j], a0[i][j], 0, 0, 0); \
      if (NB == 2) {                                                                           \
        _Pragma("unroll")                                                                      \
        for (int i = 0; i < 3; ++i)                                                            \
          a1v[i][j] = __builtin_amdgcn_mfma_f32_16x16x32_bf16(CAF[i], CB1[j], a1v[i][j], 0, 0, 0); \
      }                                                                                        \
    }                                                                                          \
    __builtin_amdgcn_s_setprio(0);                                                             \
  } while (0)

  f32x4 a0[3][2] = {};
  f32x4 a1v[3][2] = {};

  const int NT = K / 32;   // NT >= 3 at every call site
  int prm = ((l >> 4) ^ ((l >> 1) & 3)) * 8;

  bf16x8 afX[3], b0X[2], b1X[2];
  bf16x8 afY[3], b0Y[2], b1Y[2];

  GG_STAGE(0, 0);
  GG_STAGE(1, 1);
  GG_STAGE(2, 2);
  if (NB == 2) { if (w < 2) VMCNT(8); else VMCNT(6); }   // tile0 landed
  else         { if (w < 2) VMCNT(6); else VMCNT(4); }
  __builtin_amdgcn_s_barrier();
  __builtin_amdgcn_sched_barrier(0);
  GG_READ(afX, b0X, b1X, 0);

  int kt = 0, bS = 0, bR = 1;
  for (;;) {
    GG_BODY(kt, afX, b0X, b1X, afY, b0Y, b1Y, bS, bR);
    if (++kt == NT) break;
    bS = (bS + 1 == 3) ? 0 : bS + 1; bR = (bR + 1 == 3) ? 0 : bR + 1;
    GG_BODY(kt, afY, b0Y, b1Y, afX, b0X, b1X, bS, bR);
    if (++kt == NT) break;
    bS = (bS + 1 == 3) ? 0 : bS + 1; bR = (bR + 1 == 3) ? 0 : bR + 1;
  }
#undef GG_BODY
#undef GG_READ
#undef GG_STAGE

  float alpha = alphap ? alphap[0] : 1.0f;
  float* F0b = F0 ? F0 + (size_t)bz * sC : nullptr;
  float* F1b = F1 ? F1 + (size_t)bz * sC : nullptr;
  unsigned short* O0b = O0 ? O0 + (size_t)bz * sC : nullptr;
  unsigned short* O1b = O1 ? O1 + (size_t)bz * sC : nullptr;

  #pragma unroll
  for (int i = 0; i < 3; ++i) {
    #pragma unroll
    for (int j = 0; j < 2; ++j) {
      #pragma unroll
      for (int qq = 0; qq < 4; ++qq) {
        int gm = m0 + wr * 48 + i * 16 + (l >> 4) * 4 + qq;
        int gn = n0 + wc * 32 + j * 16 + (l & 15);
        if (gn >= N) continue;
        size_t oidx = (size_t)gm * N + gn;
        float v = alpha * a0[i][j][qq];
        if (bias0) v += bias0[gn];
        if (relu) v = fmaxf(v, 0.f);
        if (C0b) v += C0b[oidx];
        if (zerodiag && gm == gn) v = 0.f;
        if (F0b) F0b[oidx] = v;
        if (O0b) O0b[oidx] = f2bf(v);
        if (NB == 2) {
          float v1 = alpha * a1v[i][j][qq];
          if (bias1) v1 += bias1[gn];
          if (relu) v1 = fmaxf(v1, 0.f);
          if (F1b) F1b[oidx] = v1;
          if (O1b) O1b[oidx] = f2bf(v1);
        }
      }
    }
  }
}

// ---------------------------------------------------------------------------
// Fused dual-B MFMA SFU GEMM, 96x64 tile, reg-prefetch pipelined, swizzled
// LDS. grid (12, 64) = 768 wg = 3 wg/CU. K=2304 (weight-folded).
// ---------------------------------------------------------------------------
__global__ __launch_bounds__(256)
void sfu_mfma(const unsigned short* __restrict__ Mc,
              const unsigned short* __restrict__ Brt,
              const unsigned short* __restrict__ Bgt,
              const float* __restrict__ Xres, float* __restrict__ Z,
              unsigned short* __restrict__ Zb)
{
  __shared__ unsigned short As[3][3072];
  __shared__ unsigned short Brs[3][2048];
  __shared__ unsigned short Bgs[3][2048];
  const int K = 2304;
  const int NT = 72;
  int tid = threadIdx.x;
  int w = tid >> 6, l = tid & 63;
  int m0 = blockIdx.y * 96, n0 = blockIdx.x * 64;
  int wr = w >> 1, wc = w & 1;

  int rS = w * 16 + (l >> 2);
  int g8 = (((l & 3) ^ ((l >> 3) & 3))) * 8;
  const unsigned short* srcA0 = Mc  + (size_t)(m0 + rS) * K + g8;
  const unsigned short* srcA1 = Mc  + (size_t)(m0 + 64 + rS) * K + g8;  // w<2 only
  const unsigned short* srcR  = Brt + (size_t)(n0 + rS) * K + g8;
  const unsigned short* srcG  = Bgt + (size_t)(n0 + rS) * K + g8;
  int wb = w * 256;

#define SFU_STAGE(kt, bi) do { int kk0 = (kt) * 32;                                                                      \
    __builtin_amdgcn_global_load_lds((const unsigned int*)(srcA0 + kk0), (unsigned int*)&As[bi][0]  + wb,        16, 0, 0); \
    if (w < 2)                                                                                                           \
      __builtin_amdgcn_global_load_lds((const unsigned int*)(srcA1 + kk0), (unsigned int*)&As[bi][0] + 1024 + wb, 16, 0, 0); \
    __builtin_amdgcn_global_load_lds((const unsigned int*)(srcR  + kk0), (unsigned int*)&Brs[bi][0] + wb,        16, 0, 0); \
    __builtin_amdgcn_global_load_lds((const unsigned int*)(srcG  + kk0), (unsigned int*)&Bgs[bi][0] + wb,        16, 0, 0); \
  } while (0)

#define SFU_READ(AF, BRv, BGv, bi) do {                                                        \
    _Pragma("unroll")                                                                          \
    for (int i = 0; i < 3; ++i)                                                                \
      AF[i] = *reinterpret_cast<const bf16x8*>(&As[bi][(wr * 48 + i * 16 + (l & 15)) * 32 + prm]); \
    _Pragma("unroll")                                                                          \
    for (int j = 0; j < 2; ++j) {                                                              \
      int off = (wc * 32 + j * 16 + (l & 15)) * 32 + prm;                                      \
      BRv[j] = *reinterpret_cast<const bf16x8*>(&Brs[bi][off]);                                \
      BGv[j] = *reinterpret_cast<const bf16x8*>(&Bgs[bi][off]);                                \
    }                                                                                          \
  } while (0)

#define SFU_BODY(kt, CAF, CBR, CBG, PAF, PBR, PBG, bS, bR) do {                                \
    if ((kt) <= NT - 3) { if (w < 2) VMCNT(4); else VMCNT(3); }                                \
    else VMCNT(0);                                                                             \
    LGKM0();                                                                                   \
    __builtin_amdgcn_s_barrier();                                                              \
    __builtin_amdgcn_sched_barrier(0);                                                         \
    if ((kt) + 3 < NT) SFU_STAGE((kt) + 3, bS);                                                \
    if ((kt) + 1 < NT) SFU_READ(PAF, PBR, PBG, bR);                                            \
    __builtin_amdgcn_s_setprio(1);                                                             \
    _Pragma("unroll")                                                                          \
    for (int j = 0; j < 2; ++j) {                                                              \
      _Pragma("unroll")                                                                        \
      for (int i = 0; i < 3; ++i) {                                                            \
        aR[i][j] = __builtin_amdgcn_mfma_f32_16x16x32_bf16(CAF[i], CBR[j], aR[i][j], 0, 0, 0); \
        aG[i][j] = __builtin_amdgcn_mfma_f32_16x16x32_bf16(CAF[i], CBG[j], aG[i][j], 0, 0, 0); \
      }                                                                                        \
    }                                                                                          \
    __builtin_amdgcn_s_setprio(0);                                                             \
  } while (0)

  f32x4 aR[3][2] = {};
  f32x4 aG[3][2] = {};

  int prm = ((l >> 4) ^ ((l >> 1) & 3)) * 8;

  bf16x8 afX[3], brX[2], bgX[2];
  bf16x8 afY[3], brY[2], bgY[2];

  SFU_STAGE(0, 0);
  SFU_STAGE(1, 1);
  SFU_STAGE(2, 2);
  if (w < 2) VMCNT(8); else VMCNT(6);   // tile0 landed
  __builtin_amdgcn_s_barrier();
  __builtin_amdgcn_sched_barrier(0);
  SFU_READ(afX, brX, bgX, 0);

  int kt = 0, bS = 0, bR = 1;
  for (;;) {
    SFU_BODY(kt, afX, brX, bgX, afY, brY, bgY, bS, bR);
    if (++kt == NT) break;
    bS = (bS + 1 == 3) ? 0 : bS + 1; bR = (bR + 1 == 3) ? 0 : bR + 1;
    SFU_BODY(kt, afY, brY, bgY, afX, brX, bgX, bS, bR);
    if (++kt == NT) break;
    bS = (bS + 1 == 3) ? 0 : bS + 1; bR = (bR + 1 == 3) ? 0 : bR + 1;
  }
#undef SFU_BODY
#undef SFU_READ
#undef SFU_STAGE

  #pragma unroll
  for (int i = 0; i < 3; ++i) {
    #pragma unroll
    for (int j = 0; j < 2; ++j) {
      #pragma unroll
      for (int qq = 0; qq < 4; ++qq) {
        int gm = m0 + wr * 48 + i * 16 + (l >> 4) * 4 + qq;
        int gn = n0 + wc * 32 + j * 16 + (l & 15);
        float r = fmaxf(aR[i][j][qq], 0.f);
        float g = 1.0f / (1.0f + expf(-aG[i][j][qq]));
        float xv = Xres[(size_t)gm * 768 + gn];
        float z = r * g + (1.0f - g) * xv;
        Z[(size_t)gm * 768 + gn] = z;
        if (Zb) Zb[(size_t)gm * 768 + gn] = f2bf(z);
      }
    }
  }
}

// ---------------------------------------------------------------------------
// host side
// ---------------------------------------------------------------------------
static void launch_mfma1(const unsigned short* A, const unsigned short* Bt,
                         const float* bias, const float* alphap, const float* C0,
                         float* F0, unsigned short* O0,
                         int M, int N, int K, long sA, long sB, long sC0, long sC,
                         int relu, int zd, int batch, hipStream_t s)
{
  dim3 g((N + 63) / 64, M / 96, batch);
  mfma_gemm<1><<<g, 256, 0, s>>>(A, Bt, nullptr, bias, nullptr, alphap, C0,
                                 F0, nullptr, O0, nullptr, M, N, K, sA, sB, sC0, sC, relu, zd);
}

static void launch_mfma2(const unsigned short* A, const unsigned short* Bt0,
                         const unsigned short* Bt1, const float* bias0, const float* bias1,
                         unsigned short* O0, unsigned short* O1,
                         int M, int N, int K, long sA, long sB,
                         int relu, int batch, hipStream_t s)
{
  dim3 g((N + 63) / 64, M / 96, batch);
  mfma_gemm<2><<<g, 256, 0, s>>>(A, Bt0, Bt1, bias0, bias1, nullptr, nullptr,
                                 nullptr, nullptr, O0, O1, M, N, K, sA, sB, 0, sA,
                                 relu, 0);
}

static void launch_sfu(const float* x, const float* f, const float* Wr, const float* Wg,
                       const float* xres, float* z, unsigned short* zb,
                       unsigned short* Mc, unsigned short* Wt, hipStream_t s)
{
  concat_bf16<<<dim3(2304), 256, 0, s>>>(x, f, Mc);         // must precede Wt write (aliases f region)
  unsigned short* Wrt = Wt;
  unsigned short* Wgt = Wt + (size_t)768 * 2304;
  transp_cast2<<<dim3(12, 36, 2), 256, 0, s>>>(Wr, Wg, Wt); // folded K=2304
  sfu_mfma<<<dim3(12, 64), 256, 0, s>>>(Mc, Wrt, Wgt, xres, z, zb);
}

extern "C" void kernel_launch(void* const* d_in, const int* in_sizes, int n_in,
                              void* d_out, int out_size, void* d_ws, size_t ws_size,
                              hipStream_t stream)
{
  const int b = 8, c = 768, q = 96, d = 768, T = 2;
  const float* U   = (const float*)d_in[0];
  const float* V   = (const float*)d_in[1];
  const int*   Um  = (const int*)d_in[2];
  const int*   Vm  = (const int*)d_in[3];
  const float* Wu  = (const float*)d_in[4];
  const float* bu  = (const float*)d_in[5];
  const float* Wv  = (const float*)d_in[6];
  const float* bv  = (const float*)d_in[7];
  const float* Wri = (const float*)d_in[8];
  const float* Wgi = (const float*)d_in[9];
  const float* gi  = (const float*)d_in[10];
  const float* W1  = (const float*)d_in[11];
  const float* b1  = (const float*)d_in[12];
  const float* W2  = (const float*)d_in[13];
  const float* b2  = (const float*)d_in[14];
  const float* Wrs = (const float*)d_in[15];
  const float* Wgs = (const float*)d_in[16];
  const float* gs  = (const float*)d_in[17];
  float* out = (float*)d_out;

  const size_t big = (size_t)b * c * d;   // 4718592 == b*c*c
  const size_t smE = (size_t)b * c * q;   // 589824 == b*q*d
  float* ws   = (float*)d_ws;
  float* xbuf = ws + 0 * big;
  float* h    = ws + 1 * big;
  float* Bm   = ws + 2 * big;
  float* t1   = ws + 3 * big;             // Ctb bf16 / H1b+H2b bf16 / BmT f32 / Mc low
  float* t2   = ws + 4 * big;             // Mc high
  float* t3   = ws + 5 * big;             // xb16 / hb16 home (t3h)
  float* t4   = ws + 6 * big;             // qctx/hctx f32 ; SFU Wt bf16
  float* Ebuf = ws + 7 * big;             // persistent E (b,c,q)
  float* E0b  = Ebuf + smE;
  float* Esb  = E0b + smE;                // E^T f32 scratch
  float* spare = Esb + smE;
  float* slotE = spare + smE;             // big/2 f32: B2sb16 / hTb16
  float* WTf  = slotE + big / 2;          // weight + activation bf16 region

  unsigned short* Mc  = (unsigned short*)t1;           // 6144x2304 bf16 (t1+t2)
  unsigned short* Wt  = (unsigned short*)t4;           // SFU weights bf16 (folded)
  unsigned short* t1h = (unsigned short*)t1;           // Ctb / H1b
  unsigned short* t3h = (unsigned short*)t3;           // xb16 / hb16
  unsigned short* t3h2 = t3h + big;                    // B1sT / Bttb16
  unsigned short* slotEb = (unsigned short*)slotE;     // B2sb16 / hTb16
  unsigned short* H1b = t1h;
  unsigned short* H2b = H1b + big;
  unsigned short* WuT = (unsigned short*)WTf;
  unsigned short* WvT  = WuT  + (size_t)d * d;
  unsigned short* W1T  = WvT  + (size_t)d * d;
  unsigned short* W2T  = W1T  + (size_t)d * d;
  unsigned short* Vb16 = W2T  + (size_t)d * d;         // (b*q, d) bf16
  unsigned short* Qtbb = Vb16 + smE;                   // (b, q, d) bf16
  unsigned short* VTb  = Qtbb + smE;                   // (b, d, q) bf16
  unsigned short* EsTb = VTb  + smE;                   // (b, q, c) bf16
  unsigned short* Ettb = EsTb + smE;                   // (b, c, q) bf16

  const long cd = (long)c * d, cq = (long)c * q, qd = (long)q * d, cc = (long)c * c;
  const size_t dd = (size_t)d * d;
  const int cast_big = (int)(big / 8);
  (void)ws_size; (void)spare;

  const float* x = U;
  for (int t = 0; t < T; ++t) {
    const float* Writ = Wri + (size_t)t * 4 * dd;
    const float* Wgit = Wgi + (size_t)t * 4 * dd;
    const float* Wrst = Wrs + (size_t)t * 4 * dd;
    const float* Wgst = Wgs + (size_t)t * 4 * dd;

    // -- prep: batched weight transposes + input casts --
    transp_cast4<<<dim3(12, 12, 4), 256, 0, stream>>>(Wu + t * dd, Wv + t * dd,
                                                      W1 + t * dd, W2 + t * dd, WuT);
    if (t == 0) {
      cast_bf16<<<dim3((int)(smE / 8 / 256)), 256, 0, stream>>>(V, Vb16, (int)(smE / 8));
      transpV<<<dim3(12, 2, b), 256, 0, stream>>>(V, VTb);
      cast_bf16<<<dim3(cast_big / 256), 256, 0, stream>>>(x, t3h, cast_big);  // xb16 (U)
    }
    // t=1: t3h already holds xb16 from stage-0 Z-sfu dual write

    // 1. Ctb = relu(x @ Wu + bu) bf16 -> t1h  [M=6144 fold]
    launch_mfma1(t3h, WuT, bu + t * d, nullptr, nullptr, nullptr, t1h,
                 b * c, d, d, 0, 0, 0, 0, 1, 0, 1, stream);
    // 2. Qtb = relu(V @ Wv + bv) bf16 -> Qtbb [M=768 fold]
    launch_mfma1(Vb16, WvT, bv + t * d, nullptr, nullptr, nullptr, Qtbb,
                 b * q, d, d, 0, 0, 0, 0, 1, 0, 1, stream);
    // 3. E0 = Ctb @ Qtb^T (MFMA, N=96 clamped)
    float* e0dst = (t == 0) ? Ebuf : E0b;
    launch_mfma1(t1h, Qtbb, nullptr, nullptr, nullptr, e0dst, nullptr,
                 c, q, d, cd, qd, 0, cq, 0, 0, b, stream);
    if (t > 0) {
      // 4a. EsT bf16 = row-softmax over c of E^T
      transp_f32<<<dim3(2, 12, b), 256, 0, stream>>>(Ebuf, Esb, c, q, cq, cq);
      softmax_row_mask<<<dim3(q, b), 256, 0, stream>>>(Esb, Um, nullptr, EsTb, q, c);
      // 4b. B2s bf16 = row-softmax(mask(B_prev)) -> slotEb
      softmax_row_mask<<<dim3(c, b), 256, 0, stream>>>(Bm, Um, nullptr, slotEb, c, c);
      // 4c. E = E0 + gi * B2s @ Es  (MFMA, N=96 clamped)
      launch_mfma1(slotEb, EsTb, nullptr, gi + t, E0b, Ebuf, nullptr,
                   c, q, c, cc, cq, cq, cq, 0, 0, b, stream);
    }
    // 5. Ett bf16 = softmax_row(mask_q(E)) -> Ettb
    softmax_row_mask<<<dim3(c, b), 256, 0, stream>>>(Ebuf, Vm, nullptr, Ettb, c, q);
    // 6. qctx = Ett @ V (MFMA, K=96) -> t4 f32
    launch_mfma1(Ettb, VTb, nullptr, nullptr, nullptr, t4, nullptr,
                 c, d, q, cq, qd, 0, cd, 0, 0, b, stream);
    // 7. h = SFU(x, qctx) [MFMA], dual-writes h f32 + hb16 (t3h)
    launch_sfu(x, t4, Writ, Wgit, x, h, t3h, Mc, Wt, stream);
    // 8. H1,H2 dual-B (A = hb16) -> bf16 H1b,H2b
    launch_mfma2(t3h, W1T, W2T, b1 + t * d, b2 + t * d, H1b, H2b,
                 b * c, d, d, 0, 0, 1, 1, stream);
    // 9/10. B0 and B carry
    if (t == 0) {
      launch_mfma1(H1b, H2b, nullptr, nullptr, nullptr, Bm, nullptr,
                   c, c, d, cd, cd, 0, cc, 0, 1, b, stream);
    } else {
      launch_mfma1(H1b, H2b, nullptr, nullptr, nullptr, xbuf, nullptr,
                   c, c, d, cd, cd, 0, cc, 0, 0, b, stream);            // B0 -> xbuf
      transp_f32<<<dim3(12, 12, b), 256, 0, stream>>>(Bm, t1, c, c, cc, cc);      // B^T (H1b/H2b dead)
      softmax_row_mask<<<dim3(c, b), 256, 0, stream>>>(t1, Um, nullptr, t3h2, c, c); // B1sT bf16
      launch_mfma1(slotEb, t3h2, nullptr, gs + t, xbuf, Bm, nullptr,
                   c, c, c, cc, cc, cc, cc, 0, 1, b, stream);           // B = B0+gs*B2s@B1s
    }
    // 11. Btt bf16 = softmax_row(mask_c(B)) -> t3h2
    softmax_row_mask<<<dim3(c, b), 256, 0, stream>>>(Bm, Um, nullptr, t3h2, c, c);
    // 12. hT bf16; hctx = Btt @ h^T -> t4
    transp_cast<<<dim3(12, 12, b), 256, 0, stream>>>(h, slotEb, 768, cd, cd);
    launch_mfma1(t3h2, slotEb, nullptr, nullptr, nullptr, t4, nullptr,
                 c, d, c, cc, cd, 0, cd, 0, 0, b, stream);
    // 13. Z = SFU(h, hctx) [MFMA]; dual-write xb16 for next stage (not last)
    float* zdst = (t == T - 1) ? out : xbuf;
    unsigned short* zb16 = (t == T - 1) ? nullptr : t3h;
    launch_sfu(h, t4, Wrst, Wgst, h, zdst, zb16, Mc, Wt, stream);

    x = xbuf;
  }
}

// Round 5
// 778.572 us; speedup vs baseline: 1.4252x; 1.4252x over previous
//
#include <hip/hip_runtime.h>
#include <math.h>

#define NEGV -1e9f

typedef short bf16x8 __attribute__((ext_vector_type(8)));
typedef float f32x4 __attribute__((ext_vector_type(4)));
typedef unsigned short ushort8v __attribute__((ext_vector_type(8)));

static __device__ __forceinline__ unsigned short f2bf(float f) {
  unsigned int u = __float_as_uint(f);
  unsigned int r = (u + 0x7fffu + ((u >> 16) & 1u)) >> 16;
  return (unsigned short)r;
}

// ---------------------------------------------------------------------------
// reductions
// ---------------------------------------------------------------------------
__device__ __forceinline__ float wred_max(float v) {
  #pragma unroll
  for (int o = 32; o > 0; o >>= 1) v = fmaxf(v, __shfl_down(v, o, 64));
  return v;
}
__device__ __forceinline__ float wred_sum(float v) {
  #pragma unroll
  for (int o = 32; o > 0; o >>= 1) v += __shfl_down(v, o, 64);
  return v;
}

// ---------------------------------------------------------------------------
// masked softmax over LAST dim. X: (batch, R, Cn); mask: (batch, Cn)
// ---------------------------------------------------------------------------
__global__ __launch_bounds__(256)
void softmax_row_mask(const float* __restrict__ X, const int* __restrict__ mask,
                      float* __restrict__ Y, unsigned short* __restrict__ Ybf,
                      int R, int Cn)
{
  int bz = blockIdx.y, r = blockIdx.x, tid = threadIdx.x;
  const float* xr = X + ((size_t)bz * R + r) * Cn;
  const int*   mr = mask + (size_t)bz * Cn;
  float*       yr = Y ? (Y + ((size_t)bz * R + r) * Cn) : nullptr;
  unsigned short* yb = Ybf ? (Ybf + ((size_t)bz * R + r) * Cn) : nullptr;
  __shared__ float sred[4];

  float mx = -INFINITY;
  for (int i = tid; i < Cn; i += 256) {
    float v = (mr[i] != 0) ? xr[i] : NEGV;
    mx = fmaxf(mx, v);
  }
  float wm = wred_max(mx);
  if ((tid & 63) == 0) sred[tid >> 6] = wm;
  __syncthreads();
  mx = fmaxf(fmaxf(sred[0], sred[1]), fmaxf(sred[2], sred[3]));
  __syncthreads();

  float s = 0.f;
  for (int i = tid; i < Cn; i += 256) {
    float v = (mr[i] != 0) ? xr[i] : NEGV;
    s += expf(v - mx);
  }
  float wsv = wred_sum(s);
  if ((tid & 63) == 0) sred[tid >> 6] = wsv;
  __syncthreads();
  s = sred[0] + sred[1] + sred[2] + sred[3];
  float inv = 1.0f / s;

  for (int i = tid; i < Cn; i += 256) {
    float v = (mr[i] != 0) ? xr[i] : NEGV;
    float o = expf(v - mx) * inv;
    if (yr) yr[i] = o;
    if (yb) yb[i] = f2bf(o);
  }
}

// ---------------------------------------------------------------------------
// batched f32 tiled transpose: X (batch, R, C) -> Y (batch, C, R)
// ---------------------------------------------------------------------------
__global__ __launch_bounds__(256)
void transp_f32(const float* __restrict__ X, float* __restrict__ Y,
                int R, int C, long sX, long sY)
{
  int bz = blockIdx.z;
  X += (size_t)bz * sX;
  Y += (size_t)bz * sY;
  __shared__ float T[64][65];
  int c0 = blockIdx.x * 64, r0 = blockIdx.y * 64;
  int t = threadIdx.x;
  int tr = t >> 4, tc4 = (t & 15) * 4;
  #pragma unroll
  for (int rr = 0; rr < 4; ++rr) {
    int r = tr + rr * 16;
    float4 v = make_float4(0.f, 0.f, 0.f, 0.f);
    if (c0 + tc4 < C)
      v = *reinterpret_cast<const float4*>(X + (size_t)(r0 + r) * C + c0 + tc4);
    T[r][tc4 + 0] = v.x; T[r][tc4 + 1] = v.y;
    T[r][tc4 + 2] = v.z; T[r][tc4 + 3] = v.w;
  }
  __syncthreads();
  #pragma unroll
  for (int rr = 0; rr < 4; ++rr) {
    int cc = tr + rr * 16;
    int gc = c0 + cc;
    if (gc < C) {
      float4 o = make_float4(T[tc4 + 0][cc], T[tc4 + 1][cc], T[tc4 + 2][cc], T[tc4 + 3][cc]);
      *reinterpret_cast<float4*>(Y + (size_t)gc * R + r0 + tc4) = o;
    }
  }
}

// ---------------------------------------------------------------------------
// transpose V: (batch, 96, 768) f32 -> VTb (batch, 768, 96) bf16
// ---------------------------------------------------------------------------
__global__ __launch_bounds__(256)
void transpV(const float* __restrict__ V, unsigned short* __restrict__ VT)
{
  int bz = blockIdx.z;
  const float* Vb = V + (size_t)bz * 96 * 768;
  unsigned short* Yb = VT + (size_t)bz * 768 * 96;
  __shared__ float T[64][65];
  int c0 = blockIdx.x * 64, r0 = blockIdx.y * 64;
  int t = threadIdx.x;
  int tr = t >> 4, tc4 = (t & 15) * 4;
  #pragma unroll
  for (int rr = 0; rr < 4; ++rr) {
    int r = tr + rr * 16;
    int gr = r0 + r;
    float4 v = make_float4(0.f, 0.f, 0.f, 0.f);
    if (gr < 96)
      v = *reinterpret_cast<const float4*>(Vb + (size_t)gr * 768 + c0 + tc4);
    T[r][tc4 + 0] = v.x; T[r][tc4 + 1] = v.y;
    T[r][tc4 + 2] = v.z; T[r][tc4 + 3] = v.w;
  }
  __syncthreads();
  #pragma unroll
  for (int rr = 0; rr < 4; ++rr) {
    int cc = tr + rr * 16;
    int gc = c0 + cc;
    #pragma unroll
    for (int e = 0; e < 4; ++e) {
      int gr = r0 + tc4 + e;
      if (gr < 96) Yb[(size_t)gc * 96 + gr] = f2bf(T[tc4 + e][cc]);
    }
  }
}

// ---------------------------------------------------------------------------
// concat to bf16: Mc (6144, 2304) = [x | f | x*f] row-major bf16.
// (the x-f segment is folded into the SFU weights: m@W = x@(Wa+Wd) +
//  f@(Wb-Wd) + (x*f)@Wc  -- exact identity, K 3072 -> 2304)
// ---------------------------------------------------------------------------
__global__ __launch_bounds__(256)
void concat_bf16(const float* __restrict__ X, const float* __restrict__ F,
                 unsigned short* __restrict__ Mc)
{
  int idx = blockIdx.x * 256 + threadIdx.x;
  int m  = idx / 96;
  int kk = (idx - m * 96) * 8;
  const float* xp = X + (size_t)m * 768 + kk;
  const float* fp = F + (size_t)m * 768 + kk;
  float4 a0 = *reinterpret_cast<const float4*>(xp);
  float4 a1 = *reinterpret_cast<const float4*>(xp + 4);
  float4 b0 = *reinterpret_cast<const float4*>(fp);
  float4 b1 = *reinterpret_cast<const float4*>(fp + 4);
  float xa[8] = {a0.x, a0.y, a0.z, a0.w, a1.x, a1.y, a1.z, a1.w};
  float fa[8] = {b0.x, b0.y, b0.z, b0.w, b1.x, b1.y, b1.z, b1.w};
  ushort8v o0, o1, o2;
  #pragma unroll
  for (int i = 0; i < 8; ++i) {
    o0[i] = f2bf(xa[i]);
    o1[i] = f2bf(fa[i]);
    o2[i] = f2bf(xa[i] * fa[i]);
  }
  unsigned short* base = Mc + (size_t)m * 2304 + kk;
  *reinterpret_cast<ushort8v*>(base)        = o0;
  *reinterpret_cast<ushort8v*>(base +  768) = o1;
  *reinterpret_cast<ushort8v*>(base + 1536) = o2;
}

// ---------------------------------------------------------------------------
// batched transpose+convert for the 4 small (768x768) weights, z picks tensor
// grid (12, 12, 4)
// ---------------------------------------------------------------------------
__global__ __launch_bounds__(256)
void transp_cast4(const float* __restrict__ W0, const float* __restrict__ W1a,
                  const float* __restrict__ W2a, const float* __restrict__ W3a,
                  unsigned short* __restrict__ Wt)
{
  int z = blockIdx.z;
  const float* W = (z == 0) ? W0 : (z == 1) ? W1a : (z == 2) ? W2a : W3a;
  unsigned short* Y = Wt + (size_t)z * 768 * 768;
  __shared__ float T[64][65];
  int n0 = blockIdx.x * 64, k0 = blockIdx.y * 64;
  int t = threadIdx.x;
  int tr = t >> 4, tc4 = (t & 15) * 4;
  #pragma unroll
  for (int r = 0; r < 4; ++r) {
    int k = tr + r * 16;
    float4 v = *reinterpret_cast<const float4*>(W + (size_t)(k0 + k) * 768 + n0 + tc4);
    T[k][tc4 + 0] = v.x; T[k][tc4 + 1] = v.y; T[k][tc4 + 2] = v.z; T[k][tc4 + 3] = v.w;
  }
  __syncthreads();
  #pragma unroll
  for (int r = 0; r < 4; ++r) {
    int n = tr + r * 16;
    ushort4 o;
    o.x = f2bf(T[tc4 + 0][n]); o.y = f2bf(T[tc4 + 1][n]);
    o.z = f2bf(T[tc4 + 2][n]); o.w = f2bf(T[tc4 + 3][n]);
    *reinterpret_cast<ushort4*>(Y + (size_t)(n0 + n) * 768 + k0 + tc4) = o;
  }
}

// ---------------------------------------------------------------------------
// Folded transpose+convert for the 2 big (3072x768) SFU weights, z picks.
// Emits Wt (768, 2304) bf16 with fold:
//   k in [0,768):    Wa[k] + Wd[k]   (rows k and k+2304 of W)
//   k in [768,1536): Wb[k] - Wd[k]   (rows k and k+1536 of W)
//   k in [1536,2304): Wc[k]          (row k of W)
// grid (12, 36, 2)
// ---------------------------------------------------------------------------
__global__ __launch_bounds__(256)
void transp_cast2(const float* __restrict__ Wa, const float* __restrict__ Wb,
                  unsigned short* __restrict__ Wt)
{
  const float* W = blockIdx.z ? Wb : Wa;
  unsigned short* Y = Wt + (size_t)blockIdx.z * 768 * 2304;
  __shared__ float T[64][65];
  int n0 = blockIdx.x * 64, k0 = blockIdx.y * 64;
  int t = threadIdx.x;
  int tr = t >> 4, tc4 = (t & 15) * 4;
  #pragma unroll
  for (int r = 0; r < 4; ++r) {
    int k = tr + r * 16;
    int gk = k0 + k;
    float4 v = *reinterpret_cast<const float4*>(W + (size_t)gk * 768 + n0 + tc4);
    if (gk < 768) {
      float4 u = *reinterpret_cast<const float4*>(W + (size_t)(gk + 2304) * 768 + n0 + tc4);
      v.x += u.x; v.y += u.y; v.z += u.z; v.w += u.w;
    } else if (gk < 1536) {
      float4 u = *reinterpret_cast<const float4*>(W + (size_t)(gk + 1536) * 768 + n0 + tc4);
      v.x -= u.x; v.y -= u.y; v.z -= u.z; v.w -= u.w;
    }
    T[k][tc4 + 0] = v.x; T[k][tc4 + 1] = v.y; T[k][tc4 + 2] = v.z; T[k][tc4 + 3] = v.w;
  }
  __syncthreads();
  #pragma unroll
  for (int r = 0; r < 4; ++r) {
    int n = tr + r * 16;
    ushort4 o;
    o.x = f2bf(T[tc4 + 0][n]); o.y = f2bf(T[tc4 + 1][n]);
    o.z = f2bf(T[tc4 + 2][n]); o.w = f2bf(T[tc4 + 3][n]);
    *reinterpret_cast<ushort4*>(Y + (size_t)(n0 + n) * 2304 + k0 + tc4) = o;
  }
}

// ---------------------------------------------------------------------------
// batched transpose+convert: W (batch, K, 768) f32 -> Wt (batch, 768, K) bf16
// ---------------------------------------------------------------------------
__global__ __launch_bounds__(256)
void transp_cast(const float* __restrict__ W, unsigned short* __restrict__ Wt,
                 int K, long sW, long sWt)
{
  int bz = blockIdx.z;
  W  += (size_t)bz * sW;
  Wt += (size_t)bz * sWt;
  __shared__ float T[64][65];
  int n0 = blockIdx.x * 64, k0 = blockIdx.y * 64;
  int t = threadIdx.x;
  int tr = t >> 4, tc4 = (t & 15) * 4;
  #pragma unroll
  for (int r = 0; r < 4; ++r) {
    int k = tr + r * 16;
    float4 v = *reinterpret_cast<const float4*>(W + (size_t)(k0 + k) * 768 + n0 + tc4);
    T[k][tc4 + 0] = v.x; T[k][tc4 + 1] = v.y; T[k][tc4 + 2] = v.z; T[k][tc4 + 3] = v.w;
  }
  __syncthreads();
  #pragma unroll
  for (int r = 0; r < 4; ++r) {
    int n = tr + r * 16;
    ushort4 o;
    o.x = f2bf(T[tc4 + 0][n]); o.y = f2bf(T[tc4 + 1][n]);
    o.z = f2bf(T[tc4 + 2][n]); o.w = f2bf(T[tc4 + 3][n]);
    *reinterpret_cast<ushort4*>(Wt + (size_t)(n0 + n) * K + k0 + tc4) = o;
  }
}

// ---------------------------------------------------------------------------
// flat f32 -> bf16 cast. n8 = elems/8.
// ---------------------------------------------------------------------------
__global__ __launch_bounds__(256)
void cast_bf16(const float* __restrict__ X, unsigned short* __restrict__ Y, int n8)
{
  int idx = blockIdx.x * 256 + threadIdx.x;
  if (idx >= n8) return;
  float4 a0 = *reinterpret_cast<const float4*>(X + (size_t)idx * 8);
  float4 a1 = *reinterpret_cast<const float4*>(X + (size_t)idx * 8 + 4);
  ushort8v o;
  o[0] = f2bf(a0.x); o[1] = f2bf(a0.y); o[2] = f2bf(a0.z); o[3] = f2bf(a0.w);
  o[4] = f2bf(a1.x); o[5] = f2bf(a1.y); o[6] = f2bf(a1.z); o[7] = f2bf(a1.w);
  *reinterpret_cast<ushort8v*>(Y + (size_t)idx * 8) = o;
}

// ===========================================================================
// Swizzled LDS layout (verified r9, conflicts -> 0):
//   staging source granule pre-swizzled (gsrc = (l&3)^((l>>3)&3)), LDS dest
//   linear; read offset prm = ((l>>4)^((l>>1)&3))*8 ushorts (row bases mult
//   of 16 -> permutation row&7-invariant).
//
// R4: 512 threads, 8 waves (2 row-groups x 4 col-groups), wave tile 48x16.
// 24 waves/CU (3 blocks) vs 12 before -- TLP covers the per-iteration
// latency that R2/R3's pipeline restructures could not (both neutral/worse).
// Simple 2-buffer __syncthreads loop (R1 structure, proven best).
// Staging split: A rows 0..95 by waves 0-5; B0 by waves 0-3; B1 by waves 4-7.
// ===========================================================================

// ---------------------------------------------------------------------------
// Generic MFMA GEMM, 96x64 tile, double-buffered, BK=32, 512 thr (8 waves
// 2x4, each wave 48Mx16N: i=3), swizzled LDS.
// grid (ceil(N/64), M/96, batch). M mult 96. N clamped.
// A: (M,K) bf16 k-contig; Bt: (N,K) bf16 k-contig.
// ---------------------------------------------------------------------------
template<int NB>
__global__ __launch_bounds__(512)
void mfma_gemm(const unsigned short* __restrict__ A,
               const unsigned short* __restrict__ Bt0,
               const unsigned short* __restrict__ Bt1,
               const float* __restrict__ bias0, const float* __restrict__ bias1,
               const float* __restrict__ alphap, const float* __restrict__ C0,
               float* __restrict__ F0, float* __restrict__ F1,
               unsigned short* __restrict__ O0, unsigned short* __restrict__ O1,
               int M, int N, int K,
               long sA, long sB, long sC0, long sC,
               int relu, int zerodiag)
{
  __shared__ unsigned short As[2][3072];    // 96 x 32 (swizzled granules)
  __shared__ unsigned short Bs0[2][2048];   // 64 x 32
  __shared__ unsigned short Bs1[2][NB == 2 ? 2048 : 16];

  int bz = blockIdx.z;
  A   += (size_t)bz * sA;
  Bt0 += (size_t)bz * sB;
  if (NB == 2) Bt1 += (size_t)bz * sB;
  const float* C0b = C0 ? (C0 + (size_t)bz * sC0) : nullptr;

  int tid = threadIdx.x;
  int w = tid >> 6, l = tid & 63;
  int m0 = blockIdx.y * 96, n0 = blockIdx.x * 64;
  int wr = w >> 2, wc = w & 3;

  int g8 = (((l & 3) ^ ((l >> 3) & 3))) * 8;
  int rowA = w * 16 + (l >> 2); if (rowA > 95) rowA = 95;   // used only by w<6
  int rB = n0 + (w & 3) * 16 + (l >> 2); if (rB > N - 1) rB = N - 1;
  const unsigned short* srcA  = A + (size_t)(m0 + rowA) * K + g8;
  const unsigned short* srcB0 = Bt0 + (size_t)rB * K + g8;              // w<4
  const unsigned short* srcB1 = (NB == 2) ? Bt1 + (size_t)rB * K + g8 : nullptr; // w>=4

#define GG_STAGE(kt, bi) do { int kk0 = (kt) * 32;                                                                        \
    if (w < 6)                                                                                                            \
      __builtin_amdgcn_global_load_lds((const unsigned int*)(srcA + kk0),  (unsigned int*)&As[bi][0]  + w * 256, 16, 0, 0); \
    if (w < 4)                                                                                                            \
      __builtin_amdgcn_global_load_lds((const unsigned int*)(srcB0 + kk0), (unsigned int*)&Bs0[bi][0] + w * 256, 16, 0, 0); \
    if (NB == 2 && w >= 4)                                                                                                \
      __builtin_amdgcn_global_load_lds((const unsigned int*)(srcB1 + kk0), (unsigned int*)&Bs1[bi][0] + (w - 4) * 256, 16, 0, 0); \
  } while (0)

  f32x4 a0[3] = {};
  f32x4 a1v[3] = {};

  const int NT = K / 32;
  int prm = ((l >> 4) ^ ((l >> 1) & 3)) * 8;
  GG_STAGE(0, 0);
  __syncthreads();
  int cur = 0;
  for (int kt = 0; kt < NT; ++kt) {
    if (kt + 1 < NT) GG_STAGE(kt + 1, cur ^ 1);

    bf16x8 af[3];
    #pragma unroll
    for (int i = 0; i < 3; ++i) {
      int off = (wr * 48 + i * 16 + (l & 15)) * 32 + prm;
      af[i] = *reinterpret_cast<const bf16x8*>(&As[cur][off]);
    }
    int offB = (wc * 16 + (l & 15)) * 32 + prm;
    bf16x8 b0 = *reinterpret_cast<const bf16x8*>(&Bs0[cur][offB]);
    #pragma unroll
    for (int i = 0; i < 3; ++i)
      a0[i] = __builtin_amdgcn_mfma_f32_16x16x32_bf16(af[i], b0, a0[i], 0, 0, 0);
    if (NB == 2) {
      bf16x8 b1 = *reinterpret_cast<const bf16x8*>(&Bs1[cur][offB]);
      #pragma unroll
      for (int i = 0; i < 3; ++i)
        a1v[i] = __builtin_amdgcn_mfma_f32_16x16x32_bf16(af[i], b1, a1v[i], 0, 0, 0);
    }
    __syncthreads();
    cur ^= 1;
  }
#undef GG_STAGE

  float alpha = alphap ? alphap[0] : 1.0f;
  float* F0b = F0 ? F0 + (size_t)bz * sC : nullptr;
  float* F1b = F1 ? F1 + (size_t)bz * sC : nullptr;
  unsigned short* O0b = O0 ? O0 + (size_t)bz * sC : nullptr;
  unsigned short* O1b = O1 ? O1 + (size_t)bz * sC : nullptr;

  #pragma unroll
  for (int i = 0; i < 3; ++i) {
    #pragma unroll
    for (int qq = 0; qq < 4; ++qq) {
      int gm = m0 + wr * 48 + i * 16 + (l >> 4) * 4 + qq;
      int gn = n0 + wc * 16 + (l & 15);
      if (gn >= N) continue;
      size_t oidx = (size_t)gm * N + gn;
      float v = alpha * a0[i][qq];
      if (bias0) v += bias0[gn];
      if (relu) v = fmaxf(v, 0.f);
      if (C0b) v += C0b[oidx];
      if (zerodiag && gm == gn) v = 0.f;
      if (F0b) F0b[oidx] = v;
      if (O0b) O0b[oidx] = f2bf(v);
      if (NB == 2) {
        float v1 = alpha * a1v[i][qq];
        if (bias1) v1 += bias1[gn];
        if (relu) v1 = fmaxf(v1, 0.f);
        if (F1b) F1b[oidx] = v1;
        if (O1b) O1b[oidx] = f2bf(v1);
      }
    }
  }
}

// ---------------------------------------------------------------------------
// Fused dual-B MFMA SFU GEMM, 96x64 tile, double-buffered, swizzled LDS,
// 512 thr / 8 waves. grid (12, 64) = 768 wg = 3 wg/CU. K=2304 (folded).
// ---------------------------------------------------------------------------
__global__ __launch_bounds__(512)
void sfu_mfma(const unsigned short* __restrict__ Mc,
              const unsigned short* __restrict__ Brt,
              const unsigned short* __restrict__ Bgt,
              const float* __restrict__ Xres, float* __restrict__ Z,
              unsigned short* __restrict__ Zb)
{
  __shared__ unsigned short As[2][3072];
  __shared__ unsigned short Brs[2][2048];
  __shared__ unsigned short Bgs[2][2048];
  const int K = 2304;
  const int NT = 72;
  int tid = threadIdx.x;
  int w = tid >> 6, l = tid & 63;
  int m0 = blockIdx.y * 96, n0 = blockIdx.x * 64;
  int wr = w >> 2, wc = w & 3;

  int g8 = (((l & 3) ^ ((l >> 3) & 3))) * 8;
  int rowA = w * 16 + (l >> 2); if (rowA > 95) rowA = 95;   // used only by w<6
  int rB = n0 + (w & 3) * 16 + (l >> 2);
  const unsigned short* srcA = Mc  + (size_t)(m0 + rowA) * K + g8;
  const unsigned short* srcR = Brt + (size_t)rB * K + g8;   // w<4
  const unsigned short* srcG = Bgt + (size_t)rB * K + g8;   // w>=4

#define SFU_STAGE(kt, bi) do { int kk0 = (kt) * 32;                                                                      \
    if (w < 6)                                                                                                           \
      __builtin_amdgcn_global_load_lds((const unsigned int*)(srcA + kk0), (unsigned int*)&As[bi][0]  + w * 256, 16, 0, 0); \
    if (w < 4)                                                                                                           \
      __builtin_amdgcn_global_load_lds((const unsigned int*)(srcR + kk0), (unsigned int*)&Brs[bi][0] + w * 256, 16, 0, 0); \
    if (w >= 4)                                                                                                          \
      __builtin_amdgcn_global_load_lds((const unsigned int*)(srcG + kk0), (unsigned int*)&Bgs[bi][0] + (w - 4) * 256, 16, 0, 0); \
  } while (0)

  f32x4 aR[3] = {};
  f32x4 aG[3] = {};

  int prm = ((l >> 4) ^ ((l >> 1) & 3)) * 8;
  SFU_STAGE(0, 0);
  __syncthreads();
  int cur = 0;
  for (int kt = 0; kt < NT; ++kt) {
    if (kt + 1 < NT) SFU_STAGE(kt + 1, cur ^ 1);

    bf16x8 af[3];
    #pragma unroll
    for (int i = 0; i < 3; ++i) {
      int off = (wr * 48 + i * 16 + (l & 15)) * 32 + prm;
      af[i] = *reinterpret_cast<const bf16x8*>(&As[cur][off]);
    }
    int offB = (wc * 16 + (l & 15)) * 32 + prm;
    bf16x8 br = *reinterpret_cast<const bf16x8*>(&Brs[cur][offB]);
    bf16x8 bg = *reinterpret_cast<const bf16x8*>(&Bgs[cur][offB]);
    #pragma unroll
    for (int i = 0; i < 3; ++i) {
      aR[i] = __builtin_amdgcn_mfma_f32_16x16x32_bf16(af[i], br, aR[i], 0, 0, 0);
      aG[i] = __builtin_amdgcn_mfma_f32_16x16x32_bf16(af[i], bg, aG[i], 0, 0, 0);
    }
    __syncthreads();
    cur ^= 1;
  }
#undef SFU_STAGE

  #pragma unroll
  for (int i = 0; i < 3; ++i) {
    #pragma unroll
    for (int qq = 0; qq < 4; ++qq) {
      int gm = m0 + wr * 48 + i * 16 + (l >> 4) * 4 + qq;
      int gn = n0 + wc * 16 + (l & 15);
      float r = fmaxf(aR[i][qq], 0.f);
      float g = 1.0f / (1.0f + expf(-aG[i][qq]));
      float xv = Xres[(size_t)gm * 768 + gn];
      float z = r * g + (1.0f - g) * xv;
      Z[(size_t)gm * 768 + gn] = z;
      if (Zb) Zb[(size_t)gm * 768 + gn] = f2bf(z);
    }
  }
}

// ---------------------------------------------------------------------------
// host side
// ---------------------------------------------------------------------------
static void launch_mfma1(const unsigned short* A, const unsigned short* Bt,
                         const float* bias, const float* alphap, const float* C0,
                         float* F0, unsigned short* O0,
                         int M, int N, int K, long sA, long sB, long sC0, long sC,
                         int relu, int zd, int batch, hipStream_t s)
{
  dim3 g((N + 63) / 64, M / 96, batch);
  mfma_gemm<1><<<g, 512, 0, s>>>(A, Bt, nullptr, bias, nullptr, alphap, C0,
                                 F0, nullptr, O0, nullptr, M, N, K, sA, sB, sC0, sC, relu, zd);
}

static void launch_mfma2(const unsigned short* A, const unsigned short* Bt0,
                         const unsigned short* Bt1, const float* bias0, const float* bias1,
                         unsigned short* O0, unsigned short* O1,
                         int M, int N, int K, long sA, long sB,
                         int relu, int batch, hipStream_t s)
{
  dim3 g((N + 63) / 64, M / 96, batch);
  mfma_gemm<2><<<g, 512, 0, s>>>(A, Bt0, Bt1, bias0, bias1, nullptr, nullptr,
                                 nullptr, nullptr, O0, O1, M, N, K, sA, sB, 0, sA,
                                 relu, 0);
}

static void launch_sfu(const float* x, const float* f, const float* Wr, const float* Wg,
                       const float* xres, float* z, unsigned short* zb,
                       unsigned short* Mc, unsigned short* Wt, hipStream_t s)
{
  concat_bf16<<<dim3(2304), 256, 0, s>>>(x, f, Mc);         // must precede Wt write (aliases f region)
  unsigned short* Wrt = Wt;
  unsigned short* Wgt = Wt + (size_t)768 * 2304;
  transp_cast2<<<dim3(12, 36, 2), 256, 0, s>>>(Wr, Wg, Wt); // folded K=2304
  sfu_mfma<<<dim3(12, 64), 512, 0, s>>>(Mc, Wrt, Wgt, xres, z, zb);
}

extern "C" void kernel_launch(void* const* d_in, const int* in_sizes, int n_in,
                              void* d_out, int out_size, void* d_ws, size_t ws_size,
                              hipStream_t stream)
{
  const int b = 8, c = 768, q = 96, d = 768, T = 2;
  const float* U   = (const float*)d_in[0];
  const float* V   = (const float*)d_in[1];
  const int*   Um  = (const int*)d_in[2];
  const int*   Vm  = (const int*)d_in[3];
  const float* Wu  = (const float*)d_in[4];
  const float* bu  = (const float*)d_in[5];
  const float* Wv  = (const float*)d_in[6];
  const float* bv  = (const float*)d_in[7];
  const float* Wri = (const float*)d_in[8];
  const float* Wgi = (const float*)d_in[9];
  const float* gi  = (const float*)d_in[10];
  const float* W1  = (const float*)d_in[11];
  const float* b1  = (const float*)d_in[12];
  const float* W2  = (const float*)d_in[13];
  const float* b2  = (const float*)d_in[14];
  const float* Wrs = (const float*)d_in[15];
  const float* Wgs = (const float*)d_in[16];
  const float* gs  = (const float*)d_in[17];
  float* out = (float*)d_out;

  const size_t big = (size_t)b * c * d;   // 4718592 == b*c*c
  const size_t smE = (size_t)b * c * q;   // 589824 == b*q*d
  float* ws   = (float*)d_ws;
  float* xbuf = ws + 0 * big;
  float* h    = ws + 1 * big;
  float* Bm   = ws + 2 * big;
  float* t1   = ws + 3 * big;             // Ctb bf16 / H1b+H2b bf16 / BmT f32 / Mc low
  float* t2   = ws + 4 * big;             // Mc high
  float* t3   = ws + 5 * big;             // xb16 / hb16 home (t3h)
  float* t4   = ws + 6 * big;             // qctx/hctx f32 ; SFU Wt bf16
  float* Ebuf = ws + 7 * big;             // persistent E (b,c,q)
  float* E0b  = Ebuf + smE;
  float* Esb  = E0b + smE;                // E^T f32 scratch
  float* spare = Esb + smE;
  float* slotE = spare + smE;             // big/2 f32: B2sb16 / hTb16
  float* WTf  = slotE + big / 2;          // weight + activation bf16 region

  unsigned short* Mc  = (unsigned short*)t1;           // 6144x2304 bf16 (t1+t2)
  unsigned short* Wt  = (unsigned short*)t4;           // SFU weights bf16 (folded)
  unsigned short* t1h = (unsigned short*)t1;           // Ctb / H1b
  unsigned short* t3h = (unsigned short*)t3;           // xb16 / hb16
  unsigned short* t3h2 = t3h + big;                    // B1sT / Bttb16
  unsigned short* slotEb = (unsigned short*)slotE;     // B2sb16 / hTb16
  unsigned short* H1b = t1h;
  unsigned short* H2b = H1b + big;
  unsigned short* WuT = (unsigned short*)WTf;
  unsigned short* WvT  = WuT  + (size_t)d * d;
  unsigned short* W1T  = WvT  + (size_t)d * d;
  unsigned short* W2T  = W1T  + (size_t)d * d;
  unsigned short* Vb16 = W2T  + (size_t)d * d;         // (b*q, d) bf16
  unsigned short* Qtbb = Vb16 + smE;                   // (b, q, d) bf16
  unsigned short* VTb  = Qtbb + smE;                   // (b, d, q) bf16
  unsigned short* EsTb = VTb  + smE;                   // (b, q, c) bf16
  unsigned short* Ettb = EsTb + smE;                   // (b, c, q) bf16

  const long cd = (long)c * d, cq = (long)c * q, qd = (long)q * d, cc = (long)c * c;
  const size_t dd = (size_t)d * d;
  const int cast_big = (int)(big / 8);
  (void)ws_size; (void)spare;

  const float* x = U;
  for (int t = 0; t < T; ++t) {
    const float* Writ = Wri + (size_t)t * 4 * dd;
    const float* Wgit = Wgi + (size_t)t * 4 * dd;
    const float* Wrst = Wrs + (size_t)t * 4 * dd;
    const float* Wgst = Wgs + (size_t)t * 4 * dd;

    // -- prep: batched weight transposes + input casts --
    transp_cast4<<<dim3(12, 12, 4), 256, 0, stream>>>(Wu + t * dd, Wv + t * dd,
                                                      W1 + t * dd, W2 + t * dd, WuT);
    if (t == 0) {
      cast_bf16<<<dim3((int)(smE / 8 / 256)), 256, 0, stream>>>(V, Vb16, (int)(smE / 8));
      transpV<<<dim3(12, 2, b), 256, 0, stream>>>(V, VTb);
      cast_bf16<<<dim3(cast_big / 256), 256, 0, stream>>>(x, t3h, cast_big);  // xb16 (U)
    }
    // t=1: t3h already holds xb16 from stage-0 Z-sfu dual write

    // 1. Ctb = relu(x @ Wu + bu) bf16 -> t1h  [M=6144 fold]
    launch_mfma1(t3h, WuT, bu + t * d, nullptr, nullptr, nullptr, t1h,
                 b * c, d, d, 0, 0, 0, 0, 1, 0, 1, stream);
    // 2. Qtb = relu(V @ Wv + bv) bf16 -> Qtbb [M=768 fold]
    launch_mfma1(Vb16, WvT, bv + t * d, nullptr, nullptr, nullptr, Qtbb,
                 b * q, d, d, 0, 0, 0, 0, 1, 0, 1, stream);
    // 3. E0 = Ctb @ Qtb^T (MFMA, N=96 clamped)
    float* e0dst = (t == 0) ? Ebuf : E0b;
    launch_mfma1(t1h, Qtbb, nullptr, nullptr, nullptr, e0dst, nullptr,
                 c, q, d, cd, qd, 0, cq, 0, 0, b, stream);
    if (t > 0) {
      // 4a. EsT bf16 = row-softmax over c of E^T
      transp_f32<<<dim3(2, 12, b), 256, 0, stream>>>(Ebuf, Esb, c, q, cq, cq);
      softmax_row_mask<<<dim3(q, b), 256, 0, stream>>>(Esb, Um, nullptr, EsTb, q, c);
      // 4b. B2s bf16 = row-softmax(mask(B_prev)) -> slotEb
      softmax_row_mask<<<dim3(c, b), 256, 0, stream>>>(Bm, Um, nullptr, slotEb, c, c);
      // 4c. E = E0 + gi * B2s @ Es  (MFMA, N=96 clamped)
      launch_mfma1(slotEb, EsTb, nullptr, gi + t, E0b, Ebuf, nullptr,
                   c, q, c, cc, cq, cq, cq, 0, 0, b, stream);
    }
    // 5. Ett bf16 = softmax_row(mask_q(E)) -> Ettb
    softmax_row_mask<<<dim3(c, b), 256, 0, stream>>>(Ebuf, Vm, nullptr, Ettb, c, q);
    // 6. qctx = Ett @ V (MFMA, K=96) -> t4 f32
    launch_mfma1(Ettb, VTb, nullptr, nullptr, nullptr, t4, nullptr,
                 c, d, q, cq, qd, 0, cd, 0, 0, b, stream);
    // 7. h = SFU(x, qctx) [MFMA], dual-writes h f32 + hb16 (t3h)
    launch_sfu(x, t4, Writ, Wgit, x, h, t3h, Mc, Wt, stream);
    // 8. H1,H2 dual-B (A = hb16) -> bf16 H1b,H2b
    launch_mfma2(t3h, W1T, W2T, b1 + t * d, b2 + t * d, H1b, H2b,
                 b * c, d, d, 0, 0, 1, 1, stream);
    // 9/10. B0 and B carry
    if (t == 0) {
      launch_mfma1(H1b, H2b, nullptr, nullptr, nullptr, Bm, nullptr,
                   c, c, d, cd, cd, 0, cc, 0, 1, b, stream);
    } else {
      launch_mfma1(H1b, H2b, nullptr, nullptr, nullptr, xbuf, nullptr,
                   c, c, d, cd, cd, 0, cc, 0, 0, b, stream);            // B0 -> xbuf
      transp_f32<<<dim3(12, 12, b), 256, 0, stream>>>(Bm, t1, c, c, cc, cc);      // B^T (H1b/H2b dead)
      softmax_row_mask<<<dim3(c, b), 256, 0, stream>>>(t1, Um, nullptr, t3h2, c, c); // B1sT bf16
      launch_mfma1(slotEb, t3h2, nullptr, gs + t, xbuf, Bm, nullptr,
                   c, c, c, cc, cc, cc, cc, 0, 1, b, stream);           // B = B0+gs*B2s@B1s
    }
    // 11. Btt bf16 = softmax_row(mask_c(B)) -> t3h2
    softmax_row_mask<<<dim3(c, b), 256, 0, stream>>>(Bm, Um, nullptr, t3h2, c, c);
    // 12. hT bf16; hctx = Btt @ h^T -> t4
    transp_cast<<<dim3(12, 12, b), 256, 0, stream>>>(h, slotEb, 768, cd, cd);
    launch_mfma1(t3h2, slotEb, nullptr, nullptr, nullptr, t4, nullptr,
                 c, d, c, cc, cd, 0, cd, 0, 0, b, stream);
    // 13. Z = SFU(h, hctx) [MFMA]; dual-write xb16 for next stage (not last)
    float* zdst = (t == T - 1) ? out : xbuf;
    unsigned short* zb16 = (t == T - 1) ? nullptr : t3h;
    launch_sfu(h, t4, Wrst, Wgst, h, zdst, zb16, Mc, Wt, stream);

    x = xbuf;
  }
}

// Round 6
// 754.958 us; speedup vs baseline: 1.4697x; 1.0313x over previous
//
#include <hip/hip_runtime.h>
#include <math.h>

#define NEGV -1e9f

typedef short bf16x8 __attribute__((ext_vector_type(8)));
typedef float f32x4 __attribute__((ext_vector_type(4)));
typedef unsigned short ushort8v __attribute__((ext_vector_type(8)));

static __device__ __forceinline__ unsigned short f2bf(float f) {
  unsigned int u = __float_as_uint(f);
  unsigned int r = (u + 0x7fffu + ((u >> 16) & 1u)) >> 16;
  return (unsigned short)r;
}

// bijective XCD-chunking swizzle (m204 form): XCD x gets a contiguous chunk
// of the linear grid -> consecutive work items (sharing operand panels) land
// on the same XCD L2.
static __device__ __forceinline__ int xcd_swz(int lin, int nwg) {
  int q = nwg >> 3, r = nwg & 7;
  int x = lin & 7, i = lin >> 3;
  return (x < r) ? x * (q + 1) + i : r * (q + 1) + (x - r) * q + i;
}

// ---------------------------------------------------------------------------
// reductions
// ---------------------------------------------------------------------------
__device__ __forceinline__ float wred_max(float v) {
  #pragma unroll
  for (int o = 32; o > 0; o >>= 1) v = fmaxf(v, __shfl_down(v, o, 64));
  return v;
}
__device__ __forceinline__ float wred_sum(float v) {
  #pragma unroll
  for (int o = 32; o > 0; o >>= 1) v += __shfl_down(v, o, 64);
  return v;
}

// ---------------------------------------------------------------------------
// masked softmax over LAST dim. X: (batch, R, Cn); mask: (batch, Cn)
// ---------------------------------------------------------------------------
__global__ __launch_bounds__(256)
void softmax_row_mask(const float* __restrict__ X, const int* __restrict__ mask,
                      float* __restrict__ Y, unsigned short* __restrict__ Ybf,
                      int R, int Cn)
{
  int bz = blockIdx.y, r = blockIdx.x, tid = threadIdx.x;
  const float* xr = X + ((size_t)bz * R + r) * Cn;
  const int*   mr = mask + (size_t)bz * Cn;
  float*       yr = Y ? (Y + ((size_t)bz * R + r) * Cn) : nullptr;
  unsigned short* yb = Ybf ? (Ybf + ((size_t)bz * R + r) * Cn) : nullptr;
  __shared__ float sred[4];

  float mx = -INFINITY;
  for (int i = tid; i < Cn; i += 256) {
    float v = (mr[i] != 0) ? xr[i] : NEGV;
    mx = fmaxf(mx, v);
  }
  float wm = wred_max(mx);
  if ((tid & 63) == 0) sred[tid >> 6] = wm;
  __syncthreads();
  mx = fmaxf(fmaxf(sred[0], sred[1]), fmaxf(sred[2], sred[3]));
  __syncthreads();

  float s = 0.f;
  for (int i = tid; i < Cn; i += 256) {
    float v = (mr[i] != 0) ? xr[i] : NEGV;
    s += expf(v - mx);
  }
  float wsv = wred_sum(s);
  if ((tid & 63) == 0) sred[tid >> 6] = wsv;
  __syncthreads();
  s = sred[0] + sred[1] + sred[2] + sred[3];
  float inv = 1.0f / s;

  for (int i = tid; i < Cn; i += 256) {
    float v = (mr[i] != 0) ? xr[i] : NEGV;
    float o = expf(v - mx) * inv;
    if (yr) yr[i] = o;
    if (yb) yb[i] = f2bf(o);
  }
}

// ---------------------------------------------------------------------------
// batched f32 tiled transpose: X (batch, R, C) -> Y (batch, C, R)
// ---------------------------------------------------------------------------
__global__ __launch_bounds__(256)
void transp_f32(const float* __restrict__ X, float* __restrict__ Y,
                int R, int C, long sX, long sY)
{
  int bz = blockIdx.z;
  X += (size_t)bz * sX;
  Y += (size_t)bz * sY;
  __shared__ float T[64][65];
  int c0 = blockIdx.x * 64, r0 = blockIdx.y * 64;
  int t = threadIdx.x;
  int tr = t >> 4, tc4 = (t & 15) * 4;
  #pragma unroll
  for (int rr = 0; rr < 4; ++rr) {
    int r = tr + rr * 16;
    float4 v = make_float4(0.f, 0.f, 0.f, 0.f);
    if (c0 + tc4 < C)
      v = *reinterpret_cast<const float4*>(X + (size_t)(r0 + r) * C + c0 + tc4);
    T[r][tc4 + 0] = v.x; T[r][tc4 + 1] = v.y;
    T[r][tc4 + 2] = v.z; T[r][tc4 + 3] = v.w;
  }
  __syncthreads();
  #pragma unroll
  for (int rr = 0; rr < 4; ++rr) {
    int cc = tr + rr * 16;
    int gc = c0 + cc;
    if (gc < C) {
      float4 o = make_float4(T[tc4 + 0][cc], T[tc4 + 1][cc], T[tc4 + 2][cc], T[tc4 + 3][cc]);
      *reinterpret_cast<float4*>(Y + (size_t)gc * R + r0 + tc4) = o;
    }
  }
}

// ---------------------------------------------------------------------------
// transpose V: (batch, 96, 768) f32 -> VTb (batch, 768, 96) bf16
// ---------------------------------------------------------------------------
__global__ __launch_bounds__(256)
void transpV(const float* __restrict__ V, unsigned short* __restrict__ VT)
{
  int bz = blockIdx.z;
  const float* Vb = V + (size_t)bz * 96 * 768;
  unsigned short* Yb = VT + (size_t)bz * 768 * 96;
  __shared__ float T[64][65];
  int c0 = blockIdx.x * 64, r0 = blockIdx.y * 64;
  int t = threadIdx.x;
  int tr = t >> 4, tc4 = (t & 15) * 4;
  #pragma unroll
  for (int rr = 0; rr < 4; ++rr) {
    int r = tr + rr * 16;
    int gr = r0 + r;
    float4 v = make_float4(0.f, 0.f, 0.f, 0.f);
    if (gr < 96)
      v = *reinterpret_cast<const float4*>(Vb + (size_t)gr * 768 + c0 + tc4);
    T[r][tc4 + 0] = v.x; T[r][tc4 + 1] = v.y;
    T[r][tc4 + 2] = v.z; T[r][tc4 + 3] = v.w;
  }
  __syncthreads();
  #pragma unroll
  for (int rr = 0; rr < 4; ++rr) {
    int cc = tr + rr * 16;
    int gc = c0 + cc;
    #pragma unroll
    for (int e = 0; e < 4; ++e) {
      int gr = r0 + tc4 + e;
      if (gr < 96) Yb[(size_t)gc * 96 + gr] = f2bf(T[tc4 + e][cc]);
    }
  }
}

// ---------------------------------------------------------------------------
// concat to bf16: Mc (6144, 2304) = [x | f | x*f] row-major bf16.
// (the x-f segment is folded into the SFU weights: m@W = x@(Wa+Wd) +
//  f@(Wb-Wd) + (x*f)@Wc  -- exact identity, K 3072 -> 2304)
// ---------------------------------------------------------------------------
__global__ __launch_bounds__(256)
void concat_bf16(const float* __restrict__ X, const float* __restrict__ F,
                 unsigned short* __restrict__ Mc)
{
  int idx = blockIdx.x * 256 + threadIdx.x;
  int m  = idx / 96;
  int kk = (idx - m * 96) * 8;
  const float* xp = X + (size_t)m * 768 + kk;
  const float* fp = F + (size_t)m * 768 + kk;
  float4 a0 = *reinterpret_cast<const float4*>(xp);
  float4 a1 = *reinterpret_cast<const float4*>(xp + 4);
  float4 b0 = *reinterpret_cast<const float4*>(fp);
  float4 b1 = *reinterpret_cast<const float4*>(fp + 4);
  float xa[8] = {a0.x, a0.y, a0.z, a0.w, a1.x, a1.y, a1.z, a1.w};
  float fa[8] = {b0.x, b0.y, b0.z, b0.w, b1.x, b1.y, b1.z, b1.w};
  ushort8v o0, o1, o2;
  #pragma unroll
  for (int i = 0; i < 8; ++i) {
    o0[i] = f2bf(xa[i]);
    o1[i] = f2bf(fa[i]);
    o2[i] = f2bf(xa[i] * fa[i]);
  }
  unsigned short* base = Mc + (size_t)m * 2304 + kk;
  *reinterpret_cast<ushort8v*>(base)        = o0;
  *reinterpret_cast<ushort8v*>(base +  768) = o1;
  *reinterpret_cast<ushort8v*>(base + 1536) = o2;
}

// ---------------------------------------------------------------------------
// batched transpose+convert for the 4 small (768x768) weights, z picks tensor
// grid (12, 12, 4)
// ---------------------------------------------------------------------------
__global__ __launch_bounds__(256)
void transp_cast4(const float* __restrict__ W0, const float* __restrict__ W1a,
                  const float* __restrict__ W2a, const float* __restrict__ W3a,
                  unsigned short* __restrict__ Wt)
{
  int z = blockIdx.z;
  const float* W = (z == 0) ? W0 : (z == 1) ? W1a : (z == 2) ? W2a : W3a;
  unsigned short* Y = Wt + (size_t)z * 768 * 768;
  __shared__ float T[64][65];
  int n0 = blockIdx.x * 64, k0 = blockIdx.y * 64;
  int t = threadIdx.x;
  int tr = t >> 4, tc4 = (t & 15) * 4;
  #pragma unroll
  for (int r = 0; r < 4; ++r) {
    int k = tr + r * 16;
    float4 v = *reinterpret_cast<const float4*>(W + (size_t)(k0 + k) * 768 + n0 + tc4);
    T[k][tc4 + 0] = v.x; T[k][tc4 + 1] = v.y; T[k][tc4 + 2] = v.z; T[k][tc4 + 3] = v.w;
  }
  __syncthreads();
  #pragma unroll
  for (int r = 0; r < 4; ++r) {
    int n = tr + r * 16;
    ushort4 o;
    o.x = f2bf(T[tc4 + 0][n]); o.y = f2bf(T[tc4 + 1][n]);
    o.z = f2bf(T[tc4 + 2][n]); o.w = f2bf(T[tc4 + 3][n]);
    *reinterpret_cast<ushort4*>(Y + (size_t)(n0 + n) * 768 + k0 + tc4) = o;
  }
}

// ---------------------------------------------------------------------------
// Folded transpose+convert for the 2 big (3072x768) SFU weights, z picks.
// Emits Wt (768, 2304) bf16 with fold:
//   k in [0,768):    Wa[k] + Wd[k]   (rows k and k+2304 of W)
//   k in [768,1536): Wb[k] - Wd[k]   (rows k and k+1536 of W)
//   k in [1536,2304): Wc[k]          (row k of W)
// grid (12, 36, 2)
// ---------------------------------------------------------------------------
__global__ __launch_bounds__(256)
void transp_cast2(const float* __restrict__ Wa, const float* __restrict__ Wb,
                  unsigned short* __restrict__ Wt)
{
  const float* W = blockIdx.z ? Wb : Wa;
  unsigned short* Y = Wt + (size_t)blockIdx.z * 768 * 2304;
  __shared__ float T[64][65];
  int n0 = blockIdx.x * 64, k0 = blockIdx.y * 64;
  int t = threadIdx.x;
  int tr = t >> 4, tc4 = (t & 15) * 4;
  #pragma unroll
  for (int r = 0; r < 4; ++r) {
    int k = tr + r * 16;
    int gk = k0 + k;
    float4 v = *reinterpret_cast<const float4*>(W + (size_t)gk * 768 + n0 + tc4);
    if (gk < 768) {
      float4 u = *reinterpret_cast<const float4*>(W + (size_t)(gk + 2304) * 768 + n0 + tc4);
      v.x += u.x; v.y += u.y; v.z += u.z; v.w += u.w;
    } else if (gk < 1536) {
      float4 u = *reinterpret_cast<const float4*>(W + (size_t)(gk + 1536) * 768 + n0 + tc4);
      v.x -= u.x; v.y -= u.y; v.z -= u.z; v.w -= u.w;
    }
    T[k][tc4 + 0] = v.x; T[k][tc4 + 1] = v.y; T[k][tc4 + 2] = v.z; T[k][tc4 + 3] = v.w;
  }
  __syncthreads();
  #pragma unroll
  for (int r = 0; r < 4; ++r) {
    int n = tr + r * 16;
    ushort4 o;
    o.x = f2bf(T[tc4 + 0][n]); o.y = f2bf(T[tc4 + 1][n]);
    o.z = f2bf(T[tc4 + 2][n]); o.w = f2bf(T[tc4 + 3][n]);
    *reinterpret_cast<ushort4*>(Y + (size_t)(n0 + n) * 2304 + k0 + tc4) = o;
  }
}

// ---------------------------------------------------------------------------
// batched transpose+convert: W (batch, K, 768) f32 -> Wt (batch, 768, K) bf16
// ---------------------------------------------------------------------------
__global__ __launch_bounds__(256)
void transp_cast(const float* __restrict__ W, unsigned short* __restrict__ Wt,
                 int K, long sW, long sWt)
{
  int bz = blockIdx.z;
  W  += (size_t)bz * sW;
  Wt += (size_t)bz * sWt;
  __shared__ float T[64][65];
  int n0 = blockIdx.x * 64, k0 = blockIdx.y * 64;
  int t = threadIdx.x;
  int tr = t >> 4, tc4 = (t & 15) * 4;
  #pragma unroll
  for (int r = 0; r < 4; ++r) {
    int k = tr + r * 16;
    float4 v = *reinterpret_cast<const float4*>(W + (size_t)(k0 + k) * 768 + n0 + tc4);
    T[k][tc4 + 0] = v.x; T[k][tc4 + 1] = v.y; T[k][tc4 + 2] = v.z; T[k][tc4 + 3] = v.w;
  }
  __syncthreads();
  #pragma unroll
  for (int r = 0; r < 4; ++r) {
    int n = tr + r * 16;
    ushort4 o;
    o.x = f2bf(T[tc4 + 0][n]); o.y = f2bf(T[tc4 + 1][n]);
    o.z = f2bf(T[tc4 + 2][n]); o.w = f2bf(T[tc4 + 3][n]);
    *reinterpret_cast<ushort4*>(Wt + (size_t)(n0 + n) * K + k0 + tc4) = o;
  }
}

// ---------------------------------------------------------------------------
// flat f32 -> bf16 cast. n8 = elems/8.
// ---------------------------------------------------------------------------
__global__ __launch_bounds__(256)
void cast_bf16(const float* __restrict__ X, unsigned short* __restrict__ Y, int n8)
{
  int idx = blockIdx.x * 256 + threadIdx.x;
  if (idx >= n8) return;
  float4 a0 = *reinterpret_cast<const float4*>(X + (size_t)idx * 8);
  float4 a1 = *reinterpret_cast<const float4*>(X + (size_t)idx * 8 + 4);
  ushort8v o;
  o[0] = f2bf(a0.x); o[1] = f2bf(a0.y); o[2] = f2bf(a0.z); o[3] = f2bf(a0.w);
  o[4] = f2bf(a1.x); o[5] = f2bf(a1.y); o[6] = f2bf(a1.z); o[7] = f2bf(a1.w);
  *reinterpret_cast<ushort8v*>(Y + (size_t)idx * 8) = o;
}

// ===========================================================================
// Swizzled LDS layout (verified r9, conflicts -> 0):
//   staging source granule pre-swizzled (gsrc = (l&3)^((l>>3)&3)), LDS dest
//   linear; read offset prm = ((l>>4)^((l>>1)&3))*8 ushorts (row bases mult
//   of 16 -> permutation row&7-invariant).
//
// R5: + XCD-chunked block swizzle (panel L2 locality; FETCH was 2.3x unique)
//     + WAVES template: 8 (2x4 waves, TM=96) for big GEMMs, 4 (1x4, TM=48)
//       for the grid-starved small GEMMs (96-256 blocks -> ~2x blocks).
// ===========================================================================

// ---------------------------------------------------------------------------
// Generic MFMA GEMM, (RG*48)x64 tile, double-buffered, BK=32,
// WAVES waves (RG=WAVES/4 row groups x 4 col groups), wave tile 48x16 (i=3).
// grid (ceil(N/64), M/TM, batch). M mult TM. N clamped.
// A: (M,K) bf16 k-contig; Bt: (N,K) bf16 k-contig.
// ---------------------------------------------------------------------------
template<int NB, int WAVES>
__global__ __launch_bounds__(64 * WAVES)
void mfma_gemm(const unsigned short* __restrict__ A,
               const unsigned short* __restrict__ Bt0,
               const unsigned short* __restrict__ Bt1,
               const float* __restrict__ bias0, const float* __restrict__ bias1,
               const float* __restrict__ alphap, const float* __restrict__ C0,
               float* __restrict__ F0, float* __restrict__ F1,
               unsigned short* __restrict__ O0, unsigned short* __restrict__ O1,
               int M, int N, int K,
               long sA, long sB, long sC0, long sC,
               int relu, int zerodiag)
{
  const int RG = WAVES / 4;
  const int TM = RG * 48;
  __shared__ unsigned short As[2][TM * 32];   // TM x 32 (swizzled granules)
  __shared__ unsigned short Bs0[2][2048];     // 64 x 32
  __shared__ unsigned short Bs1[2][NB == 2 ? 2048 : 16];

  // XCD-chunked bijective block swizzle over the full linear grid
  int nx = gridDim.x, ny = gridDim.y;
  int nwg = nx * ny * gridDim.z;
  int lin = blockIdx.x + nx * (blockIdx.y + ny * blockIdx.z);
  int sw = xcd_swz(lin, nwg);
  int bxi = sw % nx; int rest = sw / nx;
  int byi = rest % ny; int bz = rest / ny;

  A   += (size_t)bz * sA;
  Bt0 += (size_t)bz * sB;
  if (NB == 2) Bt1 += (size_t)bz * sB;
  const float* C0b = C0 ? (C0 + (size_t)bz * sC0) : nullptr;

  int tid = threadIdx.x;
  int w = tid >> 6, l = tid & 63;
  int m0 = byi * TM, n0 = bxi * 64;
  int wr = w >> 2, wc = w & 3;

  int g8 = (((l & 3) ^ ((l >> 3) & 3))) * 8;
  int rowA = w * 16 + (l >> 2); if (rowA > TM - 1) rowA = TM - 1;  // used only by w < TM/16
  int rB = n0 + (w & 3) * 16 + (l >> 2); if (rB > N - 1) rB = N - 1;
  const unsigned short* srcA  = A + (size_t)(m0 + rowA) * K + g8;
  const unsigned short* srcB0 = Bt0 + (size_t)rB * K + g8;                        // w<4
  const unsigned short* srcB1 = (NB == 2) ? Bt1 + (size_t)rB * K + g8 : nullptr;  // w>=4

#define GG_STAGE(kt, bi) do { int kk0 = (kt) * 32;                                                                        \
    if (w < TM / 16)                                                                                                      \
      __builtin_amdgcn_global_load_lds((const unsigned int*)(srcA + kk0),  (unsigned int*)&As[bi][0]  + w * 256, 16, 0, 0); \
    if (w < 4)                                                                                                            \
      __builtin_amdgcn_global_load_lds((const unsigned int*)(srcB0 + kk0), (unsigned int*)&Bs0[bi][0] + w * 256, 16, 0, 0); \
    if (NB == 2 && w >= 4)                                                                                                \
      __builtin_amdgcn_global_load_lds((const unsigned int*)(srcB1 + kk0), (unsigned int*)&Bs1[bi][0] + (w - 4) * 256, 16, 0, 0); \
  } while (0)

  f32x4 a0[3] = {};
  f32x4 a1v[3] = {};

  const int NT = K / 32;
  int prm = ((l >> 4) ^ ((l >> 1) & 3)) * 8;
  GG_STAGE(0, 0);
  __syncthreads();
  int cur = 0;
  for (int kt = 0; kt < NT; ++kt) {
    if (kt + 1 < NT) GG_STAGE(kt + 1, cur ^ 1);

    bf16x8 af[3];
    #pragma unroll
    for (int i = 0; i < 3; ++i) {
      int off = (wr * 48 + i * 16 + (l & 15)) * 32 + prm;
      af[i] = *reinterpret_cast<const bf16x8*>(&As[cur][off]);
    }
    int offB = (wc * 16 + (l & 15)) * 32 + prm;
    bf16x8 b0 = *reinterpret_cast<const bf16x8*>(&Bs0[cur][offB]);
    #pragma unroll
    for (int i = 0; i < 3; ++i)
      a0[i] = __builtin_amdgcn_mfma_f32_16x16x32_bf16(af[i], b0, a0[i], 0, 0, 0);
    if (NB == 2) {
      bf16x8 b1 = *reinterpret_cast<const bf16x8*>(&Bs1[cur][offB]);
      #pragma unroll
      for (int i = 0; i < 3; ++i)
        a1v[i] = __builtin_amdgcn_mfma_f32_16x16x32_bf16(af[i], b1, a1v[i], 0, 0, 0);
    }
    __syncthreads();
    cur ^= 1;
  }
#undef GG_STAGE

  float alpha = alphap ? alphap[0] : 1.0f;
  float* F0b = F0 ? F0 + (size_t)bz * sC : nullptr;
  float* F1b = F1 ? F1 + (size_t)bz * sC : nullptr;
  unsigned short* O0b = O0 ? O0 + (size_t)bz * sC : nullptr;
  unsigned short* O1b = O1 ? O1 + (size_t)bz * sC : nullptr;

  #pragma unroll
  for (int i = 0; i < 3; ++i) {
    #pragma unroll
    for (int qq = 0; qq < 4; ++qq) {
      int gm = m0 + wr * 48 + i * 16 + (l >> 4) * 4 + qq;
      int gn = n0 + wc * 16 + (l & 15);
      if (gn >= N) continue;
      size_t oidx = (size_t)gm * N + gn;
      float v = alpha * a0[i][qq];
      if (bias0) v += bias0[gn];
      if (relu) v = fmaxf(v, 0.f);
      if (C0b) v += C0b[oidx];
      if (zerodiag && gm == gn) v = 0.f;
      if (F0b) F0b[oidx] = v;
      if (O0b) O0b[oidx] = f2bf(v);
      if (NB == 2) {
        float v1 = alpha * a1v[i][qq];
        if (bias1) v1 += bias1[gn];
        if (relu) v1 = fmaxf(v1, 0.f);
        if (F1b) F1b[oidx] = v1;
        if (O1b) O1b[oidx] = f2bf(v1);
      }
    }
  }
}

// ---------------------------------------------------------------------------
// Fused dual-B MFMA SFU GEMM, 96x64 tile, double-buffered, swizzled LDS,
// 512 thr / 8 waves, XCD-chunked blocks. grid (12, 64) = 768 wg = 3 wg/CU.
// K=2304 (weight-folded).
// ---------------------------------------------------------------------------
__global__ __launch_bounds__(512)
void sfu_mfma(const unsigned short* __restrict__ Mc,
              const unsigned short* __restrict__ Brt,
              const unsigned short* __restrict__ Bgt,
              const float* __restrict__ Xres, float* __restrict__ Z,
              unsigned short* __restrict__ Zb)
{
  __shared__ unsigned short As[2][3072];
  __shared__ unsigned short Brs[2][2048];
  __shared__ unsigned short Bgs[2][2048];
  const int K = 2304;
  const int NT = 72;

  int nx = gridDim.x, ny = gridDim.y;
  int nwg = nx * ny;
  int lin = blockIdx.x + nx * blockIdx.y;
  int sw = xcd_swz(lin, nwg);
  int bxi = sw % nx; int byi = sw / nx;

  int tid = threadIdx.x;
  int w = tid >> 6, l = tid & 63;
  int m0 = byi * 96, n0 = bxi * 64;
  int wr = w >> 2, wc = w & 3;

  int g8 = (((l & 3) ^ ((l >> 3) & 3))) * 8;
  int rowA = w * 16 + (l >> 2); if (rowA > 95) rowA = 95;   // used only by w<6
  int rB = n0 + (w & 3) * 16 + (l >> 2);
  const unsigned short* srcA = Mc  + (size_t)(m0 + rowA) * K + g8;
  const unsigned short* srcR = Brt + (size_t)rB * K + g8;   // w<4
  const unsigned short* srcG = Bgt + (size_t)rB * K + g8;   // w>=4

#define SFU_STAGE(kt, bi) do { int kk0 = (kt) * 32;                                                                      \
    if (w < 6)                                                                                                           \
      __builtin_amdgcn_global_load_lds((const unsigned int*)(srcA + kk0), (unsigned int*)&As[bi][0]  + w * 256, 16, 0, 0); \
    if (w < 4)                                                                                                           \
      __builtin_amdgcn_global_load_lds((const unsigned int*)(srcR + kk0), (unsigned int*)&Brs[bi][0] + w * 256, 16, 0, 0); \
    if (w >= 4)                                                                                                          \
      __builtin_amdgcn_global_load_lds((const unsigned int*)(srcG + kk0), (unsigned int*)&Bgs[bi][0] + (w - 4) * 256, 16, 0, 0); \
  } while (0)

  f32x4 aR[3] = {};
  f32x4 aG[3] = {};

  int prm = ((l >> 4) ^ ((l >> 1) & 3)) * 8;
  SFU_STAGE(0, 0);
  __syncthreads();
  int cur = 0;
  for (int kt = 0; kt < NT; ++kt) {
    if (kt + 1 < NT) SFU_STAGE(kt + 1, cur ^ 1);

    bf16x8 af[3];
    #pragma unroll
    for (int i = 0; i < 3; ++i) {
      int off = (wr * 48 + i * 16 + (l & 15)) * 32 + prm;
      af[i] = *reinterpret_cast<const bf16x8*>(&As[cur][off]);
    }
    int offB = (wc * 16 + (l & 15)) * 32 + prm;
    bf16x8 br = *reinterpret_cast<const bf16x8*>(&Brs[cur][offB]);
    bf16x8 bg = *reinterpret_cast<const bf16x8*>(&Bgs[cur][offB]);
    #pragma unroll
    for (int i = 0; i < 3; ++i) {
      aR[i] = __builtin_amdgcn_mfma_f32_16x16x32_bf16(af[i], br, aR[i], 0, 0, 0);
      aG[i] = __builtin_amdgcn_mfma_f32_16x16x32_bf16(af[i], bg, aG[i], 0, 0, 0);
    }
    __syncthreads();
    cur ^= 1;
  }
#undef SFU_STAGE

  #pragma unroll
  for (int i = 0; i < 3; ++i) {
    #pragma unroll
    for (int qq = 0; qq < 4; ++qq) {
      int gm = m0 + wr * 48 + i * 16 + (l >> 4) * 4 + qq;
      int gn = n0 + wc * 16 + (l & 15);
      float r = fmaxf(aR[i][qq], 0.f);
      float g = 1.0f / (1.0f + expf(-aG[i][qq]));
      float xv = Xres[(size_t)gm * 768 + gn];
      float z = r * g + (1.0f - g) * xv;
      Z[(size_t)gm * 768 + gn] = z;
      if (Zb) Zb[(size_t)gm * 768 + gn] = f2bf(z);
    }
  }
}

// ---------------------------------------------------------------------------
// host side
// ---------------------------------------------------------------------------
static void launch_mfma1(const unsigned short* A, const unsigned short* Bt,
                         const float* bias, const float* alphap, const float* C0,
                         float* F0, unsigned short* O0,
                         int M, int N, int K, long sA, long sB, long sC0, long sC,
                         int relu, int zd, int batch, int tm, hipStream_t s)
{
  dim3 g((N + 63) / 64, M / tm, batch);
  if (tm == 48)
    mfma_gemm<1, 4><<<g, 256, 0, s>>>(A, Bt, nullptr, bias, nullptr, alphap, C0,
                                      F0, nullptr, O0, nullptr, M, N, K, sA, sB, sC0, sC, relu, zd);
  else
    mfma_gemm<1, 8><<<g, 512, 0, s>>>(A, Bt, nullptr, bias, nullptr, alphap, C0,
                                      F0, nullptr, O0, nullptr, M, N, K, sA, sB, sC0, sC, relu, zd);
}

static void launch_mfma2(const unsigned short* A, const unsigned short* Bt0,
                         const unsigned short* Bt1, const float* bias0, const float* bias1,
                         unsigned short* O0, unsigned short* O1,
                         int M, int N, int K, long sA, long sB,
                         int relu, int batch, hipStream_t s)
{
  dim3 g((N + 63) / 64, M / 96, batch);
  mfma_gemm<2, 8><<<g, 512, 0, s>>>(A, Bt0, Bt1, bias0, bias1, nullptr, nullptr,
                                    nullptr, nullptr, O0, O1, M, N, K, sA, sB, 0, sA,
                                    relu, 0);
}

static void launch_sfu(const float* x, const float* f, const float* Wr, const float* Wg,
                       const float* xres, float* z, unsigned short* zb,
                       unsigned short* Mc, unsigned short* Wt, hipStream_t s)
{
  concat_bf16<<<dim3(2304), 256, 0, s>>>(x, f, Mc);         // must precede Wt write (aliases f region)
  unsigned short* Wrt = Wt;
  unsigned short* Wgt = Wt + (size_t)768 * 2304;
  transp_cast2<<<dim3(12, 36, 2), 256, 0, s>>>(Wr, Wg, Wt); // folded K=2304
  sfu_mfma<<<dim3(12, 64), 512, 0, s>>>(Mc, Wrt, Wgt, xres, z, zb);
}

extern "C" void kernel_launch(void* const* d_in, const int* in_sizes, int n_in,
                              void* d_out, int out_size, void* d_ws, size_t ws_size,
                              hipStream_t stream)
{
  const int b = 8, c = 768, q = 96, d = 768, T = 2;
  const float* U   = (const float*)d_in[0];
  const float* V   = (const float*)d_in[1];
  const int*   Um  = (const int*)d_in[2];
  const int*   Vm  = (const int*)d_in[3];
  const float* Wu  = (const float*)d_in[4];
  const float* bu  = (const float*)d_in[5];
  const float* Wv  = (const float*)d_in[6];
  const float* bv  = (const float*)d_in[7];
  const float* Wri = (const float*)d_in[8];
  const float* Wgi = (const float*)d_in[9];
  const float* gi  = (const float*)d_in[10];
  const float* W1  = (const float*)d_in[11];
  const float* b1  = (const float*)d_in[12];
  const float* W2  = (const float*)d_in[13];
  const float* b2  = (const float*)d_in[14];
  const float* Wrs = (const float*)d_in[15];
  const float* Wgs = (const float*)d_in[16];
  const float* gs  = (const float*)d_in[17];
  float* out = (float*)d_out;

  const size_t big = (size_t)b * c * d;   // 4718592 == b*c*c
  const size_t smE = (size_t)b * c * q;   // 589824 == b*q*d
  float* ws   = (float*)d_ws;
  float* xbuf = ws + 0 * big;
  float* h    = ws + 1 * big;
  float* Bm   = ws + 2 * big;
  float* t1   = ws + 3 * big;             // Ctb bf16 / H1b+H2b bf16 / BmT f32 / Mc low
  float* t2   = ws + 4 * big;             // Mc high
  float* t3   = ws + 5 * big;             // xb16 / hb16 home (t3h)
  float* t4   = ws + 6 * big;             // qctx/hctx f32 ; SFU Wt bf16
  float* Ebuf = ws + 7 * big;             // persistent E (b,c,q)
  float* E0b  = Ebuf + smE;
  float* Esb  = E0b + smE;                // E^T f32 scratch
  float* spare = Esb + smE;
  float* slotE = spare + smE;             // big/2 f32: B2sb16 / hTb16
  float* WTf  = slotE + big / 2;          // weight + activation bf16 region

  unsigned short* Mc  = (unsigned short*)t1;           // 6144x2304 bf16 (t1+t2)
  unsigned short* Wt  = (unsigned short*)t4;           // SFU weights bf16 (folded)
  unsigned short* t1h = (unsigned short*)t1;           // Ctb / H1b
  unsigned short* t3h = (unsigned short*)t3;           // xb16 / hb16
  unsigned short* t3h2 = t3h + big;                    // B1sT / Bttb16
  unsigned short* slotEb = (unsigned short*)slotE;     // B2sb16 / hTb16
  unsigned short* H1b = t1h;
  unsigned short* H2b = H1b + big;
  unsigned short* WuT = (unsigned short*)WTf;
  unsigned short* WvT  = WuT  + (size_t)d * d;
  unsigned short* W1T  = WvT  + (size_t)d * d;
  unsigned short* W2T  = W1T  + (size_t)d * d;
  unsigned short* Vb16 = W2T  + (size_t)d * d;         // (b*q, d) bf16
  unsigned short* Qtbb = Vb16 + smE;                   // (b, q, d) bf16
  unsigned short* VTb  = Qtbb + smE;                   // (b, d, q) bf16
  unsigned short* EsTb = VTb  + smE;                   // (b, q, c) bf16
  unsigned short* Ettb = EsTb + smE;                   // (b, c, q) bf16

  const long cd = (long)c * d, cq = (long)c * q, qd = (long)q * d, cc = (long)c * c;
  const size_t dd = (size_t)d * d;
  const int cast_big = (int)(big / 8);
  (void)ws_size; (void)spare;

  const float* x = U;
  for (int t = 0; t < T; ++t) {
    const float* Writ = Wri + (size_t)t * 4 * dd;
    const float* Wgit = Wgi + (size_t)t * 4 * dd;
    const float* Wrst = Wrs + (size_t)t * 4 * dd;
    const float* Wgst = Wgs + (size_t)t * 4 * dd;

    // -- prep: batched weight transposes + input casts --
    transp_cast4<<<dim3(12, 12, 4), 256, 0, stream>>>(Wu + t * dd, Wv + t * dd,
                                                      W1 + t * dd, W2 + t * dd, WuT);
    if (t == 0) {
      cast_bf16<<<dim3((int)(smE / 8 / 256)), 256, 0, stream>>>(V, Vb16, (int)(smE / 8));
      transpV<<<dim3(12, 2, b), 256, 0, stream>>>(V, VTb);
      cast_bf16<<<dim3(cast_big / 256), 256, 0, stream>>>(x, t3h, cast_big);  // xb16 (U)
    }
    // t=1: t3h already holds xb16 from stage-0 Z-sfu dual write

    // 1. Ctb = relu(x @ Wu + bu) bf16 -> t1h  [M=6144 fold]
    launch_mfma1(t3h, WuT, bu + t * d, nullptr, nullptr, nullptr, t1h,
                 b * c, d, d, 0, 0, 0, 0, 1, 0, 1, 96, stream);
    // 2. Qtb = relu(V @ Wv + bv) bf16 -> Qtbb [M=768 fold, TM=48 for blocks]
    launch_mfma1(Vb16, WvT, bv + t * d, nullptr, nullptr, nullptr, Qtbb,
                 b * q, d, d, 0, 0, 0, 0, 1, 0, 1, 48, stream);
    // 3. E0 = Ctb @ Qtb^T (MFMA, N=96 clamped, TM=48)
    float* e0dst = (t == 0) ? Ebuf : E0b;
    launch_mfma1(t1h, Qtbb, nullptr, nullptr, nullptr, e0dst, nullptr,
                 c, q, d, cd, qd, 0, cq, 0, 0, b, 48, stream);
    if (t > 0) {
      // 4a. EsT bf16 = row-softmax over c of E^T
      transp_f32<<<dim3(2, 12, b), 256, 0, stream>>>(Ebuf, Esb, c, q, cq, cq);
      softmax_row_mask<<<dim3(q, b), 256, 0, stream>>>(Esb, Um, nullptr, EsTb, q, c);
      // 4b. B2s bf16 = row-softmax(mask(B_prev)) -> slotEb
      softmax_row_mask<<<dim3(c, b), 256, 0, stream>>>(Bm, Um, nullptr, slotEb, c, c);
      // 4c. E = E0 + gi * B2s @ Es  (MFMA, N=96 clamped, TM=48)
      launch_mfma1(slotEb, EsTb, nullptr, gi + t, E0b, Ebuf, nullptr,
                   c, q, c, cc, cq, cq, cq, 0, 0, b, 48, stream);
    }
    // 5. Ett bf16 = softmax_row(mask_q(E)) -> Ettb
    softmax_row_mask<<<dim3(c, b), 256, 0, stream>>>(Ebuf, Vm, nullptr, Ettb, c, q);
    // 6. qctx = Ett @ V (MFMA, K=96) -> t4 f32
    launch_mfma1(Ettb, VTb, nullptr, nullptr, nullptr, t4, nullptr,
                 c, d, q, cq, qd, 0, cd, 0, 0, b, 96, stream);
    // 7. h = SFU(x, qctx) [MFMA], dual-writes h f32 + hb16 (t3h)
    launch_sfu(x, t4, Writ, Wgit, x, h, t3h, Mc, Wt, stream);
    // 8. H1,H2 dual-B (A = hb16) -> bf16 H1b,H2b
    launch_mfma2(t3h, W1T, W2T, b1 + t * d, b2 + t * d, H1b, H2b,
                 b * c, d, d, 0, 0, 1, 1, stream);
    // 9/10. B0 and B carry
    if (t == 0) {
      launch_mfma1(H1b, H2b, nullptr, nullptr, nullptr, Bm, nullptr,
                   c, c, d, cd, cd, 0, cc, 0, 1, b, 96, stream);
    } else {
      launch_mfma1(H1b, H2b, nullptr, nullptr, nullptr, xbuf, nullptr,
                   c, c, d, cd, cd, 0, cc, 0, 0, b, 96, stream);        // B0 -> xbuf
      transp_f32<<<dim3(12, 12, b), 256, 0, stream>>>(Bm, t1, c, c, cc, cc);      // B^T (H1b/H2b dead)
      softmax_row_mask<<<dim3(c, b), 256, 0, stream>>>(t1, Um, nullptr, t3h2, c, c); // B1sT bf16
      launch_mfma1(slotEb, t3h2, nullptr, gs + t, xbuf, Bm, nullptr,
                   c, c, c, cc, cc, cc, cc, 0, 1, b, 96, stream);       // B = B0+gs*B2s@B1s
    }
    // 11. Btt bf16 = softmax_row(mask_c(B)) -> t3h2
    softmax_row_mask<<<dim3(c, b), 256, 0, stream>>>(Bm, Um, nullptr, t3h2, c, c);
    // 12. hT bf16; hctx = Btt @ h^T -> t4
    transp_cast<<<dim3(12, 12, b), 256, 0, stream>>>(h, slotEb, 768, cd, cd);
    launch_mfma1(t3h2, slotEb, nullptr, nullptr, nullptr, t4, nullptr,
                 c, d, c, cc, cd, 0, cd, 0, 0, b, 96, stream);
    // 13. Z = SFU(h, hctx) [MFMA]; dual-write xb16 for next stage (not last)
    float* zdst = (t == T - 1) ? out : xbuf;
    unsigned short* zb16 = (t == T - 1) ? nullptr : t3h;
    launch_sfu(h, t4, Wrst, Wgst, h, zdst, zb16, Mc, Wt, stream);

    x = xbuf;
  }
}